// Round 16
// baseline (288.049 us; speedup 1.0000x reference)
//
#include <hip/hip_runtime.h>
#include <hip/hip_bf16.h>
#include <stdint.h>
#include <stddef.h>

#define B_   4
#define N_   16384
#define M_   4096
#define C1_  256
#define C2_  512
#define CIN_ 768
#define CH_  256
#define NG_  (B_*N_)   // 65536
#define NSLOT 64

typedef __attribute__((ext_vector_type(8))) short short8;
typedef __attribute__((ext_vector_type(4))) float f32x4;

__device__ __forceinline__ float bf2f(unsigned short u){
  union { unsigned int i; float f; } v; v.i = ((unsigned int)u)<<16; return v.f;
}
// pack via compiler-lowered cast (pairs into v_cvt_pk_bf16_f32 on gfx950)
__device__ __forceinline__ unsigned short f2bfh(float f){
  __hip_bfloat16 h = __float2bfloat16(f);
  return *reinterpret_cast<unsigned short*>(&h);
}

// ---------------- prep: W1/W2 -> bf16, known -> K4 ----------------
__global__ __launch_bounds__(256) void prep_k(const float* __restrict__ W1,
                                              const float* __restrict__ W2,
                                              const float* __restrict__ kn,
                                              unsigned short* __restrict__ W1b,
                                              unsigned short* __restrict__ W2b,
                                              float4* __restrict__ k4){
  int i = blockIdx.x*256 + threadIdx.x;
  if (i < CIN_*CH_) W1b[i] = f2bfh(W1[i]);
  if (i < CH_*CH_)  W2b[i] = f2bfh(W2[i]);
  if (i < B_*M_){
    float x = kn[3*i], y = kn[3*i+1], z = kn[3*i+2];
    float4 v; v.x = -2.f*x; v.y = -2.f*y; v.z = -2.f*z; v.w = x*x+y*y+z*z;
    k4[i] = v;
  }
}

// ---------------- K0: known_feats [b][c][m] f32 -> kftb [b][m][c] bf16 ----------------
__global__ __launch_bounds__(256) void kft_k(const float* __restrict__ kf,
                                             unsigned short* __restrict__ kftb){
  int m0 = blockIdx.x*64, c0 = blockIdx.y*64, b = blockIdx.z;
  __shared__ float tile[64][65];
  int t = threadIdx.x;
  #pragma unroll
  for (int p=0;p<16;p++){
    int row = p*4 + (t>>6), col = t&63;
    tile[row][col] = kf[((size_t)b*C2_ + c0+row)*M_ + m0+col];
  }
  __syncthreads();
  #pragma unroll
  for (int q=0;q<2;q++){
    int id = q*256 + t;
    int ml = id >> 3, c8 = (id & 7)*8;
    short8 o;
    #pragma unroll
    for (int e=0;e<8;++e) o[e] = (short)f2bfh(tile[c8+e][ml]);
    *(short8*)(kftb + ((size_t)b*M_ + m0+ml)*C2_ + c0 + c8) = o;
  }
}

// ---------------- K1: three_nn — 2 points/lane, LDS broadcast scan (R12 floor) ----------------
__global__ __launch_bounds__(512) void three_nn_k(const float* __restrict__ unk,
                                                  const float4* __restrict__ k4,
                                                  int* __restrict__ idx,
                                                  float* __restrict__ wgt){
  __shared__ __align__(16) char smem[65536];   // 64 KB: table, then merge arrays
  float4* kl = (float4*)smem;
  float*  sd = (float*)smem;                   // sd[24][128] after aliasing
  int*    si = (int*)(smem + 24*128*4);        // si[24][128]
  int b  = blockIdx.x >> 7;                    // 128 blocks of 128 points per batch
  int n0 = (blockIdx.x & 127) * 128;
  int t = threadIdx.x;
  int w = t >> 6, l = t & 63;                  // w = part 0..7
  const float4* src = k4 + (size_t)b*M_;
  #pragma unroll
  for (int i=0;i<8;++i) kl[i*512 + t] = src[i*512 + t];
  const float* upA = unk + ((size_t)b*N_ + n0 + l)*3;
  const float* upB = unk + ((size_t)b*N_ + n0 + 64 + l)*3;
  float ax=upA[0], ay=upA[1], az=upA[2];
  float bx=upB[0], by=upB[1], bz=upB[2];
  __syncthreads();
  float a0=1e30f,a1=1e30f,a2=1e30f; int ia0=0,ia1=0,ia2=0;
  float b0=1e30f,b1=1e30f,b2=1e30f; int ib0=0,ib1=0,ib2=0;
  const float4* kp = kl + w*512;
  const int mbase = w*512;
  #pragma unroll 8
  for (int m=0;m<512;++m){
    float4 kq = kp[m];                         // wave-uniform LDS broadcast
    int mi = mbase + m;
    float da = __builtin_fmaf(ax,kq.x, __builtin_fmaf(ay,kq.y, __builtin_fmaf(az,kq.z, kq.w)));
    float db = __builtin_fmaf(bx,kq.x, __builtin_fmaf(by,kq.y, __builtin_fmaf(bz,kq.z, kq.w)));
    {
      bool c0 = da < a0, c1 = da < a1, c2 = da < a2;
      int tA = c1 ? ia1 : mi;  ia2 = c2 ? tA : ia2;
      int tB = c0 ? ia0 : mi;  ia1 = c1 ? tB : ia1;
      ia0 = c0 ? mi : ia0;
      float n1 = __builtin_amdgcn_fmed3f(da, a0, a1);
      float n2 = __builtin_amdgcn_fmed3f(da, a1, a2);
      a0 = fminf(da, a0); a1 = n1; a2 = n2;
    }
    {
      bool c0 = db < b0, c1 = db < b1, c2 = db < b2;
      int tA = c1 ? ib1 : mi;  ib2 = c2 ? tA : ib2;
      int tB = c0 ? ib0 : mi;  ib1 = c1 ? tB : ib1;
      ib0 = c0 ? mi : ib0;
      float n1 = __builtin_amdgcn_fmed3f(db, b0, b1);
      float n2 = __builtin_amdgcn_fmed3f(db, b1, b2);
      b0 = fminf(db, b0); b1 = n1; b2 = n2;
    }
  }
  __syncthreads();                             // all table reads done -> safe to alias
  sd[(w*3+0)*128 + l] = a0;  sd[(w*3+0)*128 + 64 + l] = b0;
  sd[(w*3+1)*128 + l] = a1;  sd[(w*3+1)*128 + 64 + l] = b1;
  sd[(w*3+2)*128 + l] = a2;  sd[(w*3+2)*128 + 64 + l] = b2;
  si[(w*3+0)*128 + l] = ia0; si[(w*3+0)*128 + 64 + l] = ib0;
  si[(w*3+1)*128 + l] = ia1; si[(w*3+1)*128 + 64 + l] = ib1;
  si[(w*3+2)*128 + l] = ia2; si[(w*3+2)*128 + 64 + l] = ib2;
  __syncthreads();
  if (t < 128) {
    float bd0=1e30f,bd1=1e30f,bd2=1e30f; int bi0=0,bi1=0,bi2=0;
    #pragma unroll
    for (int q=0;q<24;++q){                    // part-major order -> stable ties
      float d = sd[q*128 + t]; int ii = si[q*128 + t];
      bool c0 = d < bd0, c1 = d < bd1, c2 = d < bd2;
      int tA = c1 ? bi1 : ii;  bi2 = c2 ? tA : bi2;
      int tB = c0 ? bi0 : ii;  bi1 = c1 ? tB : bi1;
      bi0 = c0 ? ii : bi0;
      float nd1 = __builtin_amdgcn_fmed3f(d, bd0, bd1);
      float nd2 = __builtin_amdgcn_fmed3f(d, bd1, bd2);
      bd0 = fminf(d, bd0); bd1 = nd1; bd2 = nd2;
    }
    int np = n0 + t;
    const float* upt = unk + ((size_t)b*N_ + np)*3;
    float x = upt[0], y = upt[1], z = upt[2];
    float uu0 = x*x + y*y + z*z;
    float t0 = fmaxf(bd0 + uu0, 0.f) + 1e-8f;
    float t1 = fmaxf(bd1 + uu0, 0.f) + 1e-8f;
    float t2 = fmaxf(bd2 + uu0, 0.f) + 1e-8f;
    float r0 = 1.f/t0, r1 = 1.f/t1, r2 = 1.f/t2;
    float s = r0+r1+r2;
    size_t gp = ((size_t)b*N_ + np)*3;
    idx[gp]=bi0; idx[gp+1]=bi1; idx[gp+2]=bi2;
    wgt[gp]=r0/s; wgt[gp+1]=r1/s; wgt[gp+2]=r2/s;
  }
}

// ---------------- GEMM: 1D paired grid + slotted BN stats ----------------
// MODE 1 (layer 1): B = [interp(gathered from kftb, k<512) | unknow_feats f32 (reg-staged transpose, k>=512)]
// MODE 2 (layer 2): B = raw layer-1 output with fused relu(y*scale+shift) reg-staging
template<int KTOT, int MODE>
__global__ __launch_bounds__(256) void gemm_bt_k(const unsigned short* __restrict__ Wb,
                                                 const unsigned short* __restrict__ Bt,
                                                 unsigned short* __restrict__ Yt,
                                                 float* __restrict__ sump,   // [NSLOT][256]
                                                 float* __restrict__ sqp,    // [NSLOT][256]
                                                 const float* __restrict__ scalep,
                                                 const float* __restrict__ shiftp,
                                                 const unsigned short* __restrict__ kftb,
                                                 const int* __restrict__ idx,
                                                 const float* __restrict__ wgt,
                                                 const float* __restrict__ uff){
  __shared__ short lsA[128*64];
  __shared__ short lsB[128*64];
  const int t = threadIdx.x, w = t>>6, l = t&63;
  const int nBase = (blockIdx.x>>1)*128, oBase = (blockIdx.x&1)*128;
  const int wm = w>>1, wn = w&1, rl = l&15, hi = l>>4;
  f32x4 acc[4][4];
  #pragma unroll
  for (int i=0;i<4;i++)
    #pragma unroll
    for (int j=0;j<4;j++) acc[i][j] = (f32x4){0.f,0.f,0.f,0.f};
  const int srow8 = l>>3, sch = l&7;
  // MODE1: hoist per-row gather metadata (k-independent)
  int jj0[4], jj1[4], jj2[4];
  float ww0[4], ww1[4], ww2[4];
  const unsigned short* kfb = nullptr;
  const float* ufb = nullptr;
  int nloc = 0;
  if constexpr (MODE == 1){
    int bb = nBase >> 14;               // N_=16384
    nloc = nBase & (N_-1);
    kfb = kftb + (size_t)bb*M_*C2_;
    ufb = uff + (size_t)bb*C1_*N_;
    #pragma unroll
    for (int j=0;j<4;++j){
      int row = w*8 + j*32 + srow8;
      size_t gp = (size_t)(nBase + row)*3;
      jj0[j] = idx[gp];   jj1[j] = idx[gp+1];   jj2[j] = idx[gp+2];
      ww0[j] = wgt[gp];   ww1[j] = wgt[gp+1];   ww2[j] = wgt[gp+2];
    }
  }
  for (int ks=0; ks<KTOT/64; ++ks){
    const int k0 = ks*64;
    __syncthreads();
    #pragma unroll
    for (int j=0;j<4;++j){
      int row = w*8 + j*32 + srow8;
      const unsigned short* gA = Wb + (size_t)(oBase+row)*KTOT + k0 + ((sch ^ (row&7))<<3);
      __builtin_amdgcn_global_load_lds((const __attribute__((address_space(1))) unsigned int*)gA,
          (__attribute__((address_space(3))) unsigned int*)(lsA + w*512 + j*2048), 16, 0, 0);
    }
    if constexpr (MODE == 1){
      if (k0 < C2_){
        // fused three_interpolate: gather 3 rows from kftb, blend, write swizzled LDS
        #pragma unroll
        for (int j=0;j<4;++j){
          int row = w*8 + j*32 + srow8;
          int chb = k0 + ((sch ^ (row&7))<<3);
          const short8 a0 = *(const short8*)(kfb + (size_t)jj0[j]*C2_ + chb);
          const short8 a1 = *(const short8*)(kfb + (size_t)jj1[j]*C2_ + chb);
          const short8 a2 = *(const short8*)(kfb + (size_t)jj2[j]*C2_ + chb);
          float w0 = ww0[j], w1 = ww1[j], w2 = ww2[j];
          short8 o;
          #pragma unroll
          for (int e=0;e<8;++e){
            float f = w0*bf2f((unsigned short)a0[e])
                    + w1*bf2f((unsigned short)a1[e])
                    + w2*bf2f((unsigned short)a2[e]);
            o[e] = (short)f2bfh(f);
          }
          *(short8*)(lsB + w*512 + j*2048 + l*8) = o;
        }
      } else {
        // fused transpose of unknow_feats [c][n] f32 -> B rows (k>=512)
        #pragma unroll
        for (int j=0;j<4;++j){
          int row = w*8 + j*32 + srow8;
          int cb = (k0 - C2_) + ((sch ^ (row&7))<<3);
          const float* up = ufb + (size_t)cb*N_ + (nloc + row);
          short8 o;
          #pragma unroll
          for (int e=0;e<8;++e) o[e] = (short)f2bfh(up[(size_t)e*N_]);
          *(short8*)(lsB + w*512 + j*2048 + l*8) = o;
        }
      }
    }
    if constexpr (MODE == 2){
      #pragma unroll
      for (int j=0;j<4;++j){
        int row = w*8 + j*32 + srow8;
        int chb = k0 + ((sch ^ (row&7))<<3);
        const short8 v = *(const short8*)(Bt + (size_t)(nBase+row)*KTOT + chb);
        float4 sc0 = *(const float4*)(scalep + chb);
        float4 sc1 = *(const float4*)(scalep + chb + 4);
        float4 sh0 = *(const float4*)(shiftp + chb);
        float4 sh1 = *(const float4*)(shiftp + chb + 4);
        short8 o;
        float f0 = bf2f((unsigned short)v[0])*sc0.x + sh0.x; o[0] = (short)f2bfh(f0 > 0.f ? f0 : 0.f);
        float f1 = bf2f((unsigned short)v[1])*sc0.y + sh0.y; o[1] = (short)f2bfh(f1 > 0.f ? f1 : 0.f);
        float f2 = bf2f((unsigned short)v[2])*sc0.z + sh0.z; o[2] = (short)f2bfh(f2 > 0.f ? f2 : 0.f);
        float f3 = bf2f((unsigned short)v[3])*sc0.w + sh0.w; o[3] = (short)f2bfh(f3 > 0.f ? f3 : 0.f);
        float f4 = bf2f((unsigned short)v[4])*sc1.x + sh1.x; o[4] = (short)f2bfh(f4 > 0.f ? f4 : 0.f);
        float f5 = bf2f((unsigned short)v[5])*sc1.y + sh1.y; o[5] = (short)f2bfh(f5 > 0.f ? f5 : 0.f);
        float f6 = bf2f((unsigned short)v[6])*sc1.z + sh1.z; o[6] = (short)f2bfh(f6 > 0.f ? f6 : 0.f);
        float f7 = bf2f((unsigned short)v[7])*sc1.w + sh1.w; o[7] = (short)f2bfh(f7 > 0.f ? f7 : 0.f);
        *(short8*)(lsB + w*512 + j*2048 + l*8) = o;
      }
    }
    __syncthreads();
    #pragma unroll
    for (int kk=0;kk<2;++kk){
      short8 af[4], bfr[4];
      const int pc = ((kk*4 + hi) ^ (rl&7)) << 3;
      #pragma unroll
      for (int mi=0;mi<4;++mi) af[mi]  = *(const short8*)(lsA + (wm*64 + mi*16 + rl)*64 + pc);
      #pragma unroll
      for (int ni=0;ni<4;++ni) bfr[ni] = *(const short8*)(lsB + (wn*64 + ni*16 + rl)*64 + pc);
      #pragma unroll
      for (int mi=0;mi<4;++mi)
        #pragma unroll
        for (int ni=0;ni<4;++ni)
          acc[mi][ni] = __builtin_amdgcn_mfma_f32_16x16x32_bf16(af[mi], bfr[ni], acc[mi][ni], 0,0,0);
    }
  }
  // C-write (bf16)
  #pragma unroll
  for (int mi=0;mi<4;++mi)
    #pragma unroll
    for (int ni=0;ni<4;++ni){
      int n = nBase + wn*64 + ni*16 + rl;
      int o = oBase + wm*64 + mi*16 + hi*4;
      unsigned int lo = (unsigned int)f2bfh(acc[mi][ni][0]) | ((unsigned int)f2bfh(acc[mi][ni][1])<<16);
      unsigned int hi2= (unsigned int)f2bfh(acc[mi][ni][2]) | ((unsigned int)f2bfh(acc[mi][ni][3])<<16);
      uint2 vv; vv.x = lo; vv.y = hi2;
      *(uint2*)(Yt + (size_t)n*256 + o) = vv;
    }
  // fused BN stats -> slotted partial arrays (low contention)
  float s_[4][4], q_[4][4];
  #pragma unroll
  for (int mi=0;mi<4;++mi)
    #pragma unroll
    for (int j=0;j<4;++j){
      float s0 = acc[mi][0][j] + acc[mi][1][j] + acc[mi][2][j] + acc[mi][3][j];
      float q0 = acc[mi][0][j]*acc[mi][0][j];
      q0 = __builtin_fmaf(acc[mi][1][j], acc[mi][1][j], q0);
      q0 = __builtin_fmaf(acc[mi][2][j], acc[mi][2][j], q0);
      q0 = __builtin_fmaf(acc[mi][3][j], acc[mi][3][j], q0);
      s_[mi][j] = s0; q_[mi][j] = q0;
    }
  #pragma unroll
  for (int off=1; off<16; off<<=1){
    #pragma unroll
    for (int mi=0;mi<4;++mi)
      #pragma unroll
      for (int j=0;j<4;++j){
        s_[mi][j] += __shfl_xor(s_[mi][j], off);
        q_[mi][j] += __shfl_xor(q_[mi][j], off);
      }
  }
  if (rl == 0){
    const int slot = (blockIdx.x>>1) & (NSLOT-1);
    #pragma unroll
    for (int mi=0;mi<4;++mi)
      #pragma unroll
      for (int j=0;j<4;++j){
        int o = oBase + wm*64 + mi*16 + hi*4 + j;
        atomicAdd(&sump[slot*256 + o], s_[mi][j]);
        atomicAdd(&sqp[slot*256 + o],  q_[mi][j]);
      }
  }
}

// ---------------- finalize: reduce slots -> BN scale/shift ----------------
__global__ __launch_bounds__(256) void finalize_k(const float* __restrict__ sump,
                                                  const float* __restrict__ sqp,
                                                  const float* __restrict__ g,
                                                  const float* __restrict__ bt,
                                                  float* __restrict__ scale,
                                                  float* __restrict__ shift){
  int t = threadIdx.x;
  float s = 0.f, q = 0.f;
  #pragma unroll 8
  for (int k=0;k<NSLOT;++k){
    s += sump[k*256 + t];
    q += sqp[k*256 + t];
  }
  float mean = s * (1.f/65536.f);
  float var  = q * (1.f/65536.f) - mean*mean;
  float sc = g[t] * rsqrtf(var + 1e-5f);
  scale[t] = sc;
  shift[t] = bt[t] - mean*sc;
}

// ---------------- final: y2T [n][256] bf16 -> out [b][256][N] f32 ----------------
__global__ __launch_bounds__(256) void out_k(const unsigned short* __restrict__ Yt,
                                             const float* __restrict__ scale,
                                             const float* __restrict__ shift,
                                             float* __restrict__ out){
  int gn0 = blockIdx.x*64;
  int o0  = blockIdx.y*64;
  int b = gn0 >> 14, n0 = gn0 & (N_-1);
  __shared__ unsigned short tile[64][66];
  int t = threadIdx.x;
  #pragma unroll
  for (int p=0;p<4;++p){
    int nl = p*16 + (t>>4), ol = (t&15)*4;
    const unsigned short* src = Yt + (size_t)(gn0+nl)*256 + o0 + ol;
    uint2 vv = *(const uint2*)src;
    tile[nl][ol+0] = (unsigned short)(vv.x & 0xffff);
    tile[nl][ol+1] = (unsigned short)(vv.x >> 16);
    tile[nl][ol+2] = (unsigned short)(vv.y & 0xffff);
    tile[nl][ol+3] = (unsigned short)(vv.y >> 16);
  }
  __syncthreads();
  #pragma unroll
  for (int p=0;p<4;++p){
    int ol = p*16 + (t>>4), nl = (t&15)*4;
    float sc = scale[o0+ol], sh = shift[o0+ol];
    float4 r;
    float f0 = bf2f(tile[nl+0][ol])*sc + sh; r.x = f0 > 0.f ? f0 : 0.f;
    float f1 = bf2f(tile[nl+1][ol])*sc + sh; r.y = f1 > 0.f ? f1 : 0.f;
    float f2v= bf2f(tile[nl+2][ol])*sc + sh; r.z = f2v > 0.f ? f2v : 0.f;
    float f3 = bf2f(tile[nl+3][ol])*sc + sh; r.w = f3 > 0.f ? f3 : 0.f;
    *(float4*)(out + ((size_t)(b*256 + o0+ol))*N_ + n0 + nl) = r;
  }
}

// ---------------- host launch ----------------
extern "C" void kernel_launch(void* const* d_in, const int* in_sizes, int n_in,
                              void* d_out, int out_size, void* d_ws, size_t ws_size,
                              hipStream_t stream) {
  const float* unknown     = (const float*)d_in[0];
  const float* known       = (const float*)d_in[1];
  const float* unknow_f    = (const float*)d_in[2];
  const float* known_f     = (const float*)d_in[3];
  const float* W1          = (const float*)d_in[4];
  // d_in[5] = b1 (cancels under training-mode BN)
  const float* g1          = (const float*)d_in[6];
  const float* bt1         = (const float*)d_in[7];
  const float* W2          = (const float*)d_in[8];
  // d_in[9] = b2 (cancels)
  const float* g2          = (const float*)d_in[10];
  const float* bt2         = (const float*)d_in[11];
  float* out = (float*)d_out;

  char* ws = (char*)d_ws;
  const size_t szY    = (size_t)NG_*256*2;        //  33554432 per buffer
  const size_t szKftb = (size_t)B_*M_*C2_*2;      //  16777216
  const size_t szIdx  = (size_t)NG_*3*4;
  const size_t szPart = (size_t)NSLOT*256*4;      //  65536 per array
  const size_t o_Y2   = 0;                         // y2 output
  const size_t o_Y    = szY;                       // y1T (raw layer-1 output)
  const size_t o_kftb = o_Y + szY;
  const size_t o_idx  = o_kftb + szKftb;
  const size_t o_wgt  = o_idx + szIdx;
  const size_t o_W1b  = o_wgt + szIdx;
  const size_t o_W2b  = o_W1b + (size_t)CIN_*CH_*2;
  const size_t o_st   = o_W2b + (size_t)CH_*CH_*2; // 4 partial arrays + 4 scale/shift
  const size_t o_k4   = o_st + 4*szPart + 4*256*sizeof(float);

  unsigned short* Y2   = (unsigned short*)(ws + o_Y2);
  unsigned short* Y    = (unsigned short*)(ws + o_Y);    // y1T raw
  unsigned short* kftb = (unsigned short*)(ws + o_kftb);
  int*            idx  = (int*)(ws + o_idx);
  float*          wgt  = (float*)(ws + o_wgt);
  unsigned short* W1b  = (unsigned short*)(ws + o_W1b);
  unsigned short* W2b  = (unsigned short*)(ws + o_W2b);
  float* st = (float*)(ws + o_st);
  float4* k4 = (float4*)(ws + o_k4);
  float *sum1p = st;                    // [64][256]
  float *sq1p  = st + NSLOT*256;
  float *sum2p = st + 2*NSLOT*256;
  float *sq2p  = st + 3*NSLOT*256;
  float *scale1 = st + 4*NSLOT*256;
  float *shift1 = scale1 + 256;
  float *scale2 = scale1 + 512;
  float *shift2 = scale1 + 768;

  hipMemsetAsync(st, 0, 4*szPart, stream);

  prep_k<<<768, 256, 0, stream>>>(W1, W2, known, W1b, W2b, k4);
  kft_k<<<dim3(M_/64, C2_/64, B_), 256, 0, stream>>>(known_f, kftb);
  three_nn_k<<<B_*(N_/128), 512, 0, stream>>>(unknown, k4, idx, wgt);

  gemm_bt_k<CIN_, 1><<<NG_/64, 256, 0, stream>>>(W1b, nullptr, Y, sum1p, sq1p,
                                                 nullptr, nullptr, kftb, idx, wgt, unknow_f);
  finalize_k<<<1, 256, 0, stream>>>(sum1p, sq1p, g1, bt1, scale1, shift1);

  gemm_bt_k<CH_, 2><<<NG_/64, 256, 0, stream>>>(W2b, Y, Y2, sum2p, sq2p,
                                                scale1, shift1, nullptr, nullptr, nullptr, nullptr);
  finalize_k<<<1, 256, 0, stream>>>(sum2p, sq2p, g2, bt2, scale2, shift2);
  out_k<<<dim3(NG_/64, 4), 256, 0, stream>>>(Y2, scale2, shift2, out);
}

// Round 17
// 255.543 us; speedup vs baseline: 1.1272x; 1.1272x over previous
//
#include <hip/hip_runtime.h>
#include <hip/hip_bf16.h>
#include <stdint.h>
#include <stddef.h>

#define B_   4
#define N_   16384
#define M_   4096
#define C1_  256
#define C2_  512
#define CIN_ 768
#define CH_  256
#define NG_  (B_*N_)   // 65536
#define NSLOT 64

typedef __attribute__((ext_vector_type(8))) short short8;
typedef __attribute__((ext_vector_type(4))) float f32x4;

__device__ __forceinline__ float bf2f(unsigned short u){
  union { unsigned int i; float f; } v; v.i = ((unsigned int)u)<<16; return v.f;
}
// pack via compiler-lowered cast (pairs into v_cvt_pk_bf16_f32 on gfx950)
__device__ __forceinline__ unsigned short f2bfh(float f){
  __hip_bfloat16 h = __float2bfloat16(f);
  return *reinterpret_cast<unsigned short*>(&h);
}

// ---------------- prep: W1/W2 -> bf16, known -> K4 ----------------
__global__ __launch_bounds__(256) void prep_k(const float* __restrict__ W1,
                                              const float* __restrict__ W2,
                                              const float* __restrict__ kn,
                                              unsigned short* __restrict__ W1b,
                                              unsigned short* __restrict__ W2b,
                                              float4* __restrict__ k4){
  int i = blockIdx.x*256 + threadIdx.x;
  if (i < CIN_*CH_) W1b[i] = f2bfh(W1[i]);
  if (i < CH_*CH_)  W2b[i] = f2bfh(W2[i]);
  if (i < B_*M_){
    float x = kn[3*i], y = kn[3*i+1], z = kn[3*i+2];
    float4 v; v.x = -2.f*x; v.y = -2.f*y; v.z = -2.f*z; v.w = x*x+y*y+z*z;
    k4[i] = v;
  }
}

// ---------------- K0: known_feats [b][c][m] f32 -> kftb [b][m][c] bf16 ----------------
__global__ __launch_bounds__(256) void kft_k(const float* __restrict__ kf,
                                             unsigned short* __restrict__ kftb){
  int m0 = blockIdx.x*64, c0 = blockIdx.y*64, b = blockIdx.z;
  __shared__ float tile[64][65];
  int t = threadIdx.x;
  #pragma unroll
  for (int p=0;p<16;p++){
    int row = p*4 + (t>>6), col = t&63;
    tile[row][col] = kf[((size_t)b*C2_ + c0+row)*M_ + m0+col];
  }
  __syncthreads();
  #pragma unroll
  for (int q=0;q<2;q++){
    int id = q*256 + t;
    int ml = id >> 3, c8 = (id & 7)*8;
    short8 o;
    #pragma unroll
    for (int e=0;e<8;++e) o[e] = (short)f2bfh(tile[c8+e][ml]);
    *(short8*)(kftb + ((size_t)b*M_ + m0+ml)*C2_ + c0 + c8) = o;
  }
}

// ---------------- K1: three_nn — 2 points/lane, LDS broadcast scan (R12 floor) ----------------
__global__ __launch_bounds__(512) void three_nn_k(const float* __restrict__ unk,
                                                  const float4* __restrict__ k4,
                                                  int* __restrict__ idx,
                                                  float* __restrict__ wgt){
  __shared__ __align__(16) char smem[65536];   // 64 KB: table, then merge arrays
  float4* kl = (float4*)smem;
  float*  sd = (float*)smem;                   // sd[24][128] after aliasing
  int*    si = (int*)(smem + 24*128*4);        // si[24][128]
  int b  = blockIdx.x >> 7;                    // 128 blocks of 128 points per batch
  int n0 = (blockIdx.x & 127) * 128;
  int t = threadIdx.x;
  int w = t >> 6, l = t & 63;                  // w = part 0..7
  const float4* src = k4 + (size_t)b*M_;
  #pragma unroll
  for (int i=0;i<8;++i) kl[i*512 + t] = src[i*512 + t];
  const float* upA = unk + ((size_t)b*N_ + n0 + l)*3;
  const float* upB = unk + ((size_t)b*N_ + n0 + 64 + l)*3;
  float ax=upA[0], ay=upA[1], az=upA[2];
  float bx=upB[0], by=upB[1], bz=upB[2];
  __syncthreads();
  float a0=1e30f,a1=1e30f,a2=1e30f; int ia0=0,ia1=0,ia2=0;
  float b0=1e30f,b1=1e30f,b2=1e30f; int ib0=0,ib1=0,ib2=0;
  const float4* kp = kl + w*512;
  const int mbase = w*512;
  #pragma unroll 8
  for (int m=0;m<512;++m){
    float4 kq = kp[m];                         // wave-uniform LDS broadcast
    int mi = mbase + m;
    float da = __builtin_fmaf(ax,kq.x, __builtin_fmaf(ay,kq.y, __builtin_fmaf(az,kq.z, kq.w)));
    float db = __builtin_fmaf(bx,kq.x, __builtin_fmaf(by,kq.y, __builtin_fmaf(bz,kq.z, kq.w)));
    {
      bool c0 = da < a0, c1 = da < a1, c2 = da < a2;
      int tA = c1 ? ia1 : mi;  ia2 = c2 ? tA : ia2;
      int tB = c0 ? ia0 : mi;  ia1 = c1 ? tB : ia1;
      ia0 = c0 ? mi : ia0;
      float n1 = __builtin_amdgcn_fmed3f(da, a0, a1);
      float n2 = __builtin_amdgcn_fmed3f(da, a1, a2);
      a0 = fminf(da, a0); a1 = n1; a2 = n2;
    }
    {
      bool c0 = db < b0, c1 = db < b1, c2 = db < b2;
      int tA = c1 ? ib1 : mi;  ib2 = c2 ? tA : ib2;
      int tB = c0 ? ib0 : mi;  ib1 = c1 ? tB : ib1;
      ib0 = c0 ? mi : ib0;
      float n1 = __builtin_amdgcn_fmed3f(db, b0, b1);
      float n2 = __builtin_amdgcn_fmed3f(db, b1, b2);
      b0 = fminf(db, b0); b1 = n1; b2 = n2;
    }
  }
  __syncthreads();                             // all table reads done -> safe to alias
  sd[(w*3+0)*128 + l] = a0;  sd[(w*3+0)*128 + 64 + l] = b0;
  sd[(w*3+1)*128 + l] = a1;  sd[(w*3+1)*128 + 64 + l] = b1;
  sd[(w*3+2)*128 + l] = a2;  sd[(w*3+2)*128 + 64 + l] = b2;
  si[(w*3+0)*128 + l] = ia0; si[(w*3+0)*128 + 64 + l] = ib0;
  si[(w*3+1)*128 + l] = ia1; si[(w*3+1)*128 + 64 + l] = ib1;
  si[(w*3+2)*128 + l] = ia2; si[(w*3+2)*128 + 64 + l] = ib2;
  __syncthreads();
  if (t < 128) {
    float bd0=1e30f,bd1=1e30f,bd2=1e30f; int bi0=0,bi1=0,bi2=0;
    #pragma unroll
    for (int q=0;q<24;++q){                    // part-major order -> stable ties
      float d = sd[q*128 + t]; int ii = si[q*128 + t];
      bool c0 = d < bd0, c1 = d < bd1, c2 = d < bd2;
      int tA = c1 ? bi1 : ii;  bi2 = c2 ? tA : bi2;
      int tB = c0 ? bi0 : ii;  bi1 = c1 ? tB : bi1;
      bi0 = c0 ? ii : bi0;
      float nd1 = __builtin_amdgcn_fmed3f(d, bd0, bd1);
      float nd2 = __builtin_amdgcn_fmed3f(d, bd1, bd2);
      bd0 = fminf(d, bd0); bd1 = nd1; bd2 = nd2;
    }
    int np = n0 + t;
    const float* upt = unk + ((size_t)b*N_ + np)*3;
    float x = upt[0], y = upt[1], z = upt[2];
    float uu0 = x*x + y*y + z*z;
    float t0 = fmaxf(bd0 + uu0, 0.f) + 1e-8f;
    float t1 = fmaxf(bd1 + uu0, 0.f) + 1e-8f;
    float t2 = fmaxf(bd2 + uu0, 0.f) + 1e-8f;
    float r0 = 1.f/t0, r1 = 1.f/t1, r2 = 1.f/t2;
    float s = r0+r1+r2;
    size_t gp = ((size_t)b*N_ + np)*3;
    idx[gp]=bi0; idx[gp+1]=bi1; idx[gp+2]=bi2;
    wgt[gp]=r0/s; wgt[gp+1]=r1/s; wgt[gp+2]=r2/s;
  }
}

// ---------------- K2 (slim): unknow_feats [b][c][n] -> uft [b][n][256] bf16 ----------------
__global__ __launch_bounds__(256) void uft_k(const float* __restrict__ uf,
                                             unsigned short* __restrict__ uft){
  int b  = blockIdx.x >> 8;
  int n0 = (blockIdx.x & 255) * 64;
  int t = threadIdx.x;
  __shared__ float tile[64][65];
  for (int cc=0; cc<4; ++cc){
    int c0 = cc*64;
    __syncthreads();
    #pragma unroll
    for (int p=0;p<16;p++){
      int row = p*4 + (t>>6), col = t&63;
      tile[row][col] = uf[((size_t)b*C1_ + c0+row)*N_ + n0+col];
    }
    __syncthreads();
    #pragma unroll
    for (int q=0;q<2;q++){
      int id = q*256 + t;
      int nl = id >> 3, c8 = (id & 7)*8;
      short8 o;
      #pragma unroll
      for (int e=0;e<8;++e) o[e] = (short)f2bfh(tile[c8+e][nl]);
      *(short8*)(uft + ((size_t)b*N_ + n0+nl)*CH_ + c0 + c8) = o;
    }
  }
}

// ---------------- GEMM: 1D paired grid + slotted BN stats ----------------
// MODE 1 (layer 1): B = [interp(gathered from kftb, k<512) | uft (global_load_lds, k>=512)]
// MODE 2 (layer 2): B = raw layer-1 output with fused relu(y*scale+shift) reg-staging
template<int KTOT, int MODE>
__global__ __launch_bounds__(256) void gemm_bt_k(const unsigned short* __restrict__ Wb,
                                                 const unsigned short* __restrict__ Bt,
                                                 unsigned short* __restrict__ Yt,
                                                 float* __restrict__ sump,   // [NSLOT][256]
                                                 float* __restrict__ sqp,    // [NSLOT][256]
                                                 const float* __restrict__ scalep,
                                                 const float* __restrict__ shiftp,
                                                 const unsigned short* __restrict__ kftb,
                                                 const int* __restrict__ idx,
                                                 const float* __restrict__ wgt){
  __shared__ short lsA[128*64];
  __shared__ short lsB[128*64];
  const int t = threadIdx.x, w = t>>6, l = t&63;
  const int nBase = (blockIdx.x>>1)*128, oBase = (blockIdx.x&1)*128;
  const int wm = w>>1, wn = w&1, rl = l&15, hi = l>>4;
  f32x4 acc[4][4];
  #pragma unroll
  for (int i=0;i<4;i++)
    #pragma unroll
    for (int j=0;j<4;j++) acc[i][j] = (f32x4){0.f,0.f,0.f,0.f};
  const int srow8 = l>>3, sch = l&7;
  // MODE1: hoist per-row gather metadata (k-independent)
  int jj0[4], jj1[4], jj2[4];
  float ww0[4], ww1[4], ww2[4];
  const unsigned short* kfb = nullptr;
  if constexpr (MODE == 1){
    kfb = kftb + (size_t)(nBase >> 14)*M_*C2_;
    #pragma unroll
    for (int j=0;j<4;++j){
      int row = w*8 + j*32 + srow8;
      size_t gp = (size_t)(nBase + row)*3;
      jj0[j] = idx[gp];   jj1[j] = idx[gp+1];   jj2[j] = idx[gp+2];
      ww0[j] = wgt[gp];   ww1[j] = wgt[gp+1];   ww2[j] = wgt[gp+2];
    }
  }
  for (int ks=0; ks<KTOT/64; ++ks){
    const int k0 = ks*64;
    __syncthreads();
    #pragma unroll
    for (int j=0;j<4;++j){
      int row = w*8 + j*32 + srow8;
      const unsigned short* gA = Wb + (size_t)(oBase+row)*KTOT + k0 + ((sch ^ (row&7))<<3);
      __builtin_amdgcn_global_load_lds((const __attribute__((address_space(1))) unsigned int*)gA,
          (__attribute__((address_space(3))) unsigned int*)(lsA + w*512 + j*2048), 16, 0, 0);
      if constexpr (MODE == 1){
        if (k0 >= C2_){
          const unsigned short* gB = Bt + (size_t)(nBase+row)*CH_ + (k0 - C2_) + ((sch ^ (row&7))<<3);
          __builtin_amdgcn_global_load_lds((const __attribute__((address_space(1))) unsigned int*)gB,
              (__attribute__((address_space(3))) unsigned int*)(lsB + w*512 + j*2048), 16, 0, 0);
        }
      }
    }
    if constexpr (MODE == 1){
      if (k0 < C2_){
        // fused three_interpolate: gather 3 rows from kftb, blend, write swizzled LDS
        #pragma unroll
        for (int j=0;j<4;++j){
          int row = w*8 + j*32 + srow8;
          int chb = k0 + ((sch ^ (row&7))<<3);
          const short8 a0 = *(const short8*)(kfb + (size_t)jj0[j]*C2_ + chb);
          const short8 a1 = *(const short8*)(kfb + (size_t)jj1[j]*C2_ + chb);
          const short8 a2 = *(const short8*)(kfb + (size_t)jj2[j]*C2_ + chb);
          float w0 = ww0[j], w1 = ww1[j], w2 = ww2[j];
          short8 o;
          #pragma unroll
          for (int e=0;e<8;++e){
            float f = w0*bf2f((unsigned short)a0[e])
                    + w1*bf2f((unsigned short)a1[e])
                    + w2*bf2f((unsigned short)a2[e]);
            o[e] = (short)f2bfh(f);
          }
          *(short8*)(lsB + w*512 + j*2048 + l*8) = o;
        }
      }
    }
    if constexpr (MODE == 2){
      #pragma unroll
      for (int j=0;j<4;++j){
        int row = w*8 + j*32 + srow8;
        int chb = k0 + ((sch ^ (row&7))<<3);
        const short8 v = *(const short8*)(Bt + (size_t)(nBase+row)*KTOT + chb);
        float4 sc0 = *(const float4*)(scalep + chb);
        float4 sc1 = *(const float4*)(scalep + chb + 4);
        float4 sh0 = *(const float4*)(shiftp + chb);
        float4 sh1 = *(const float4*)(shiftp + chb + 4);
        short8 o;
        float f0 = bf2f((unsigned short)v[0])*sc0.x + sh0.x; o[0] = (short)f2bfh(f0 > 0.f ? f0 : 0.f);
        float f1 = bf2f((unsigned short)v[1])*sc0.y + sh0.y; o[1] = (short)f2bfh(f1 > 0.f ? f1 : 0.f);
        float f2 = bf2f((unsigned short)v[2])*sc0.z + sh0.z; o[2] = (short)f2bfh(f2 > 0.f ? f2 : 0.f);
        float f3 = bf2f((unsigned short)v[3])*sc0.w + sh0.w; o[3] = (short)f2bfh(f3 > 0.f ? f3 : 0.f);
        float f4 = bf2f((unsigned short)v[4])*sc1.x + sh1.x; o[4] = (short)f2bfh(f4 > 0.f ? f4 : 0.f);
        float f5 = bf2f((unsigned short)v[5])*sc1.y + sh1.y; o[5] = (short)f2bfh(f5 > 0.f ? f5 : 0.f);
        float f6 = bf2f((unsigned short)v[6])*sc1.z + sh1.z; o[6] = (short)f2bfh(f6 > 0.f ? f6 : 0.f);
        float f7 = bf2f((unsigned short)v[7])*sc1.w + sh1.w; o[7] = (short)f2bfh(f7 > 0.f ? f7 : 0.f);
        *(short8*)(lsB + w*512 + j*2048 + l*8) = o;
      }
    }
    __syncthreads();
    #pragma unroll
    for (int kk=0;kk<2;++kk){
      short8 af[4], bfr[4];
      const int pc = ((kk*4 + hi) ^ (rl&7)) << 3;
      #pragma unroll
      for (int mi=0;mi<4;++mi) af[mi]  = *(const short8*)(lsA + (wm*64 + mi*16 + rl)*64 + pc);
      #pragma unroll
      for (int ni=0;ni<4;++ni) bfr[ni] = *(const short8*)(lsB + (wn*64 + ni*16 + rl)*64 + pc);
      #pragma unroll
      for (int mi=0;mi<4;++mi)
        #pragma unroll
        for (int ni=0;ni<4;++ni)
          acc[mi][ni] = __builtin_amdgcn_mfma_f32_16x16x32_bf16(af[mi], bfr[ni], acc[mi][ni], 0,0,0);
    }
  }
  // C-write (bf16)
  #pragma unroll
  for (int mi=0;mi<4;++mi)
    #pragma unroll
    for (int ni=0;ni<4;++ni){
      int n = nBase + wn*64 + ni*16 + rl;
      int o = oBase + wm*64 + mi*16 + hi*4;
      unsigned int lo = (unsigned int)f2bfh(acc[mi][ni][0]) | ((unsigned int)f2bfh(acc[mi][ni][1])<<16);
      unsigned int hi2= (unsigned int)f2bfh(acc[mi][ni][2]) | ((unsigned int)f2bfh(acc[mi][ni][3])<<16);
      uint2 vv; vv.x = lo; vv.y = hi2;
      *(uint2*)(Yt + (size_t)n*256 + o) = vv;
    }
  // fused BN stats -> slotted partial arrays (low contention)
  float s_[4][4], q_[4][4];
  #pragma unroll
  for (int mi=0;mi<4;++mi)
    #pragma unroll
    for (int j=0;j<4;++j){
      float s0 = acc[mi][0][j] + acc[mi][1][j] + acc[mi][2][j] + acc[mi][3][j];
      float q0 = acc[mi][0][j]*acc[mi][0][j];
      q0 = __builtin_fmaf(acc[mi][1][j], acc[mi][1][j], q0);
      q0 = __builtin_fmaf(acc[mi][2][j], acc[mi][2][j], q0);
      q0 = __builtin_fmaf(acc[mi][3][j], acc[mi][3][j], q0);
      s_[mi][j] = s0; q_[mi][j] = q0;
    }
  #pragma unroll
  for (int off=1; off<16; off<<=1){
    #pragma unroll
    for (int mi=0;mi<4;++mi)
      #pragma unroll
      for (int j=0;j<4;++j){
        s_[mi][j] += __shfl_xor(s_[mi][j], off);
        q_[mi][j] += __shfl_xor(q_[mi][j], off);
      }
  }
  if (rl == 0){
    const int slot = (blockIdx.x>>1) & (NSLOT-1);
    #pragma unroll
    for (int mi=0;mi<4;++mi)
      #pragma unroll
      for (int j=0;j<4;++j){
        int o = oBase + wm*64 + mi*16 + hi*4 + j;
        atomicAdd(&sump[slot*256 + o], s_[mi][j]);
        atomicAdd(&sqp[slot*256 + o],  q_[mi][j]);
      }
  }
}

// ---------------- finalize: reduce slots -> BN scale/shift ----------------
__global__ __launch_bounds__(256) void finalize_k(const float* __restrict__ sump,
                                                  const float* __restrict__ sqp,
                                                  const float* __restrict__ g,
                                                  const float* __restrict__ bt,
                                                  float* __restrict__ scale,
                                                  float* __restrict__ shift){
  int t = threadIdx.x;
  float s = 0.f, q = 0.f;
  #pragma unroll 8
  for (int k=0;k<NSLOT;++k){
    s += sump[k*256 + t];
    q += sqp[k*256 + t];
  }
  float mean = s * (1.f/65536.f);
  float var  = q * (1.f/65536.f) - mean*mean;
  float sc = g[t] * rsqrtf(var + 1e-5f);
  scale[t] = sc;
  shift[t] = bt[t] - mean*sc;
}

// ---------------- final: y2T [n][256] bf16 -> out [b][256][N] f32 ----------------
__global__ __launch_bounds__(256) void out_k(const unsigned short* __restrict__ Yt,
                                             const float* __restrict__ scale,
                                             const float* __restrict__ shift,
                                             float* __restrict__ out){
  int gn0 = blockIdx.x*64;
  int o0  = blockIdx.y*64;
  int b = gn0 >> 14, n0 = gn0 & (N_-1);
  __shared__ unsigned short tile[64][66];
  int t = threadIdx.x;
  #pragma unroll
  for (int p=0;p<4;++p){
    int nl = p*16 + (t>>4), ol = (t&15)*4;
    const unsigned short* src = Yt + (size_t)(gn0+nl)*256 + o0 + ol;
    uint2 vv = *(const uint2*)src;
    tile[nl][ol+0] = (unsigned short)(vv.x & 0xffff);
    tile[nl][ol+1] = (unsigned short)(vv.x >> 16);
    tile[nl][ol+2] = (unsigned short)(vv.y & 0xffff);
    tile[nl][ol+3] = (unsigned short)(vv.y >> 16);
  }
  __syncthreads();
  #pragma unroll
  for (int p=0;p<4;++p){
    int ol = p*16 + (t>>4), nl = (t&15)*4;
    float sc = scale[o0+ol], sh = shift[o0+ol];
    float4 r;
    float f0 = bf2f(tile[nl+0][ol])*sc + sh; r.x = f0 > 0.f ? f0 : 0.f;
    float f1 = bf2f(tile[nl+1][ol])*sc + sh; r.y = f1 > 0.f ? f1 : 0.f;
    float f2v= bf2f(tile[nl+2][ol])*sc + sh; r.z = f2v > 0.f ? f2v : 0.f;
    float f3 = bf2f(tile[nl+3][ol])*sc + sh; r.w = f3 > 0.f ? f3 : 0.f;
    *(float4*)(out + ((size_t)(b*256 + o0+ol))*N_ + n0 + nl) = r;
  }
}

// ---------------- host launch ----------------
extern "C" void kernel_launch(void* const* d_in, const int* in_sizes, int n_in,
                              void* d_out, int out_size, void* d_ws, size_t ws_size,
                              hipStream_t stream) {
  const float* unknown     = (const float*)d_in[0];
  const float* known       = (const float*)d_in[1];
  const float* unknow_f    = (const float*)d_in[2];
  const float* known_f     = (const float*)d_in[3];
  const float* W1          = (const float*)d_in[4];
  // d_in[5] = b1 (cancels under training-mode BN)
  const float* g1          = (const float*)d_in[6];
  const float* bt1         = (const float*)d_in[7];
  const float* W2          = (const float*)d_in[8];
  // d_in[9] = b2 (cancels)
  const float* g2          = (const float*)d_in[10];
  const float* bt2         = (const float*)d_in[11];
  float* out = (float*)d_out;

  char* ws = (char*)d_ws;
  const size_t szUft  = (size_t)NG_*CH_*2;        //  33554432 (uft, later y2)
  const size_t szY    = (size_t)NG_*256*2;        //  33554432
  const size_t szKftb = (size_t)B_*M_*C2_*2;      //  16777216
  const size_t szIdx  = (size_t)NG_*3*4;
  const size_t szPart = (size_t)NSLOT*256*4;      //  65536 per array
  const size_t o_Uft  = 0;                         // later reused for y2 output
  const size_t o_Y    = szUft;                     // y1T (raw layer-1 output)
  const size_t o_kftb = o_Y + szY;
  const size_t o_idx  = o_kftb + szKftb;
  const size_t o_wgt  = o_idx + szIdx;
  const size_t o_W1b  = o_wgt + szIdx;
  const size_t o_W2b  = o_W1b + (size_t)CIN_*CH_*2;
  const size_t o_st   = o_W2b + (size_t)CH_*CH_*2; // 4 partial arrays + 4 scale/shift
  const size_t o_k4   = o_st + 4*szPart + 4*256*sizeof(float);

  unsigned short* Uft  = (unsigned short*)(ws + o_Uft);
  unsigned short* Y2   = (unsigned short*)(ws + o_Uft);  // reuse (uft dead after GEMM1)
  unsigned short* Y    = (unsigned short*)(ws + o_Y);    // y1T raw
  unsigned short* kftb = (unsigned short*)(ws + o_kftb);
  int*            idx  = (int*)(ws + o_idx);
  float*          wgt  = (float*)(ws + o_wgt);
  unsigned short* W1b  = (unsigned short*)(ws + o_W1b);
  unsigned short* W2b  = (unsigned short*)(ws + o_W2b);
  float* st = (float*)(ws + o_st);
  float4* k4 = (float4*)(ws + o_k4);
  float *sum1p = st;                    // [64][256]
  float *sq1p  = st + NSLOT*256;
  float *sum2p = st + 2*NSLOT*256;
  float *sq2p  = st + 3*NSLOT*256;
  float *scale1 = st + 4*NSLOT*256;
  float *shift1 = scale1 + 256;
  float *scale2 = scale1 + 512;
  float *shift2 = scale1 + 768;

  hipMemsetAsync(st, 0, 4*szPart, stream);

  prep_k<<<768, 256, 0, stream>>>(W1, W2, known, W1b, W2b, k4);
  kft_k<<<dim3(M_/64, C2_/64, B_), 256, 0, stream>>>(known_f, kftb);
  three_nn_k<<<B_*(N_/128), 512, 0, stream>>>(unknown, k4, idx, wgt);
  uft_k<<<B_*(N_/64), 256, 0, stream>>>(unknow_f, Uft);

  gemm_bt_k<CIN_, 1><<<NG_/64, 256, 0, stream>>>(W1b, Uft, Y, sum1p, sq1p,
                                                 nullptr, nullptr, kftb, idx, wgt);
  finalize_k<<<1, 256, 0, stream>>>(sum1p, sq1p, g1, bt1, scale1, shift1);

  gemm_bt_k<CH_, 2><<<NG_/64, 256, 0, stream>>>(W2b, Y, Y2, sum2p, sq2p,
                                                scale1, shift1, nullptr, nullptr, nullptr);
  finalize_k<<<1, 256, 0, stream>>>(sum2p, sq2p, g2, bt2, scale2, shift2);
  out_k<<<dim3(NG_/64, 4), 256, 0, stream>>>(Y2, scale2, shift2, out);
}

// Round 18
// 246.531 us; speedup vs baseline: 1.1684x; 1.0366x over previous
//
#include <hip/hip_runtime.h>
#include <hip/hip_bf16.h>
#include <stdint.h>
#include <stddef.h>

#define B_   4
#define N_   16384
#define M_   4096
#define C1_  256
#define C2_  512
#define CIN_ 768
#define CH_  256
#define NG_  (B_*N_)   // 65536
#define NSLOT 64

typedef __attribute__((ext_vector_type(8))) short short8;
typedef __attribute__((ext_vector_type(4))) float f32x4;

__device__ __forceinline__ float bf2f(unsigned short u){
  union { unsigned int i; float f; } v; v.i = ((unsigned int)u)<<16; return v.f;
}
// pack via compiler-lowered cast (pairs into v_cvt_pk_bf16_f32 on gfx950)
__device__ __forceinline__ unsigned short f2bfh(float f){
  __hip_bfloat16 h = __float2bfloat16(f);
  return *reinterpret_cast<unsigned short*>(&h);
}

// ---------------- prep: W1/W2 -> bf16, known -> K4 ----------------
__global__ __launch_bounds__(256) void prep_k(const float* __restrict__ W1,
                                              const float* __restrict__ W2,
                                              const float* __restrict__ kn,
                                              unsigned short* __restrict__ W1b,
                                              unsigned short* __restrict__ W2b,
                                              float4* __restrict__ k4){
  int i = blockIdx.x*256 + threadIdx.x;
  if (i < CIN_*CH_) W1b[i] = f2bfh(W1[i]);
  if (i < CH_*CH_)  W2b[i] = f2bfh(W2[i]);
  if (i < B_*M_){
    float x = kn[3*i], y = kn[3*i+1], z = kn[3*i+2];
    float4 v; v.x = -2.f*x; v.y = -2.f*y; v.z = -2.f*z; v.w = x*x+y*y+z*z;
    k4[i] = v;
  }
}

// ---------------- K0: known_feats [b][c][m] f32 -> kftb [b][m][c] bf16 ----------------
__global__ __launch_bounds__(256) void kft_k(const float* __restrict__ kf,
                                             unsigned short* __restrict__ kftb){
  int m0 = blockIdx.x*64, c0 = blockIdx.y*64, b = blockIdx.z;
  __shared__ float tile[64][65];
  int t = threadIdx.x;
  #pragma unroll
  for (int p=0;p<16;p++){
    int row = p*4 + (t>>6), col = t&63;
    tile[row][col] = kf[((size_t)b*C2_ + c0+row)*M_ + m0+col];
  }
  __syncthreads();
  #pragma unroll
  for (int q=0;q<2;q++){
    int id = q*256 + t;
    int ml = id >> 3, c8 = (id & 7)*8;
    short8 o;
    #pragma unroll
    for (int e=0;e<8;++e) o[e] = (short)f2bfh(tile[c8+e][ml]);
    *(short8*)(kftb + ((size_t)b*M_ + m0+ml)*C2_ + c0 + c8) = o;
  }
}

// ---------------- K1: three_nn — 2 points/lane, LDS broadcast scan (R12 floor) ----------------
__global__ __launch_bounds__(512) void three_nn_k(const float* __restrict__ unk,
                                                  const float4* __restrict__ k4,
                                                  int* __restrict__ idx,
                                                  float* __restrict__ wgt){
  __shared__ __align__(16) char smem[65536];   // 64 KB: table, then merge arrays
  float4* kl = (float4*)smem;
  float*  sd = (float*)smem;                   // sd[24][128] after aliasing
  int*    si = (int*)(smem + 24*128*4);        // si[24][128]
  int b  = blockIdx.x >> 7;                    // 128 blocks of 128 points per batch
  int n0 = (blockIdx.x & 127) * 128;
  int t = threadIdx.x;
  int w = t >> 6, l = t & 63;                  // w = part 0..7
  const float4* src = k4 + (size_t)b*M_;
  #pragma unroll
  for (int i=0;i<8;++i) kl[i*512 + t] = src[i*512 + t];
  const float* upA = unk + ((size_t)b*N_ + n0 + l)*3;
  const float* upB = unk + ((size_t)b*N_ + n0 + 64 + l)*3;
  float ax=upA[0], ay=upA[1], az=upA[2];
  float bx=upB[0], by=upB[1], bz=upB[2];
  __syncthreads();
  float a0=1e30f,a1=1e30f,a2=1e30f; int ia0=0,ia1=0,ia2=0;
  float b0=1e30f,b1=1e30f,b2=1e30f; int ib0=0,ib1=0,ib2=0;
  const float4* kp = kl + w*512;
  const int mbase = w*512;
  #pragma unroll 8
  for (int m=0;m<512;++m){
    float4 kq = kp[m];                         // wave-uniform LDS broadcast
    int mi = mbase + m;
    float da = __builtin_fmaf(ax,kq.x, __builtin_fmaf(ay,kq.y, __builtin_fmaf(az,kq.z, kq.w)));
    float db = __builtin_fmaf(bx,kq.x, __builtin_fmaf(by,kq.y, __builtin_fmaf(bz,kq.z, kq.w)));
    {
      bool c0 = da < a0, c1 = da < a1, c2 = da < a2;
      int tA = c1 ? ia1 : mi;  ia2 = c2 ? tA : ia2;
      int tB = c0 ? ia0 : mi;  ia1 = c1 ? tB : ia1;
      ia0 = c0 ? mi : ia0;
      float n1 = __builtin_amdgcn_fmed3f(da, a0, a1);
      float n2 = __builtin_amdgcn_fmed3f(da, a1, a2);
      a0 = fminf(da, a0); a1 = n1; a2 = n2;
    }
    {
      bool c0 = db < b0, c1 = db < b1, c2 = db < b2;
      int tA = c1 ? ib1 : mi;  ib2 = c2 ? tA : ib2;
      int tB = c0 ? ib0 : mi;  ib1 = c1 ? tB : ib1;
      ib0 = c0 ? mi : ib0;
      float n1 = __builtin_amdgcn_fmed3f(db, b0, b1);
      float n2 = __builtin_amdgcn_fmed3f(db, b1, b2);
      b0 = fminf(db, b0); b1 = n1; b2 = n2;
    }
  }
  __syncthreads();                             // all table reads done -> safe to alias
  sd[(w*3+0)*128 + l] = a0;  sd[(w*3+0)*128 + 64 + l] = b0;
  sd[(w*3+1)*128 + l] = a1;  sd[(w*3+1)*128 + 64 + l] = b1;
  sd[(w*3+2)*128 + l] = a2;  sd[(w*3+2)*128 + 64 + l] = b2;
  si[(w*3+0)*128 + l] = ia0; si[(w*3+0)*128 + 64 + l] = ib0;
  si[(w*3+1)*128 + l] = ia1; si[(w*3+1)*128 + 64 + l] = ib1;
  si[(w*3+2)*128 + l] = ia2; si[(w*3+2)*128 + 64 + l] = ib2;
  __syncthreads();
  if (t < 128) {
    float bd0=1e30f,bd1=1e30f,bd2=1e30f; int bi0=0,bi1=0,bi2=0;
    #pragma unroll
    for (int q=0;q<24;++q){                    // part-major order -> stable ties
      float d = sd[q*128 + t]; int ii = si[q*128 + t];
      bool c0 = d < bd0, c1 = d < bd1, c2 = d < bd2;
      int tA = c1 ? bi1 : ii;  bi2 = c2 ? tA : bi2;
      int tB = c0 ? bi0 : ii;  bi1 = c1 ? tB : bi1;
      bi0 = c0 ? ii : bi0;
      float nd1 = __builtin_amdgcn_fmed3f(d, bd0, bd1);
      float nd2 = __builtin_amdgcn_fmed3f(d, bd1, bd2);
      bd0 = fminf(d, bd0); bd1 = nd1; bd2 = nd2;
    }
    int np = n0 + t;
    const float* upt = unk + ((size_t)b*N_ + np)*3;
    float x = upt[0], y = upt[1], z = upt[2];
    float uu0 = x*x + y*y + z*z;
    float t0 = fmaxf(bd0 + uu0, 0.f) + 1e-8f;
    float t1 = fmaxf(bd1 + uu0, 0.f) + 1e-8f;
    float t2 = fmaxf(bd2 + uu0, 0.f) + 1e-8f;
    float r0 = 1.f/t0, r1 = 1.f/t1, r2 = 1.f/t2;
    float s = r0+r1+r2;
    size_t gp = ((size_t)b*N_ + np)*3;
    idx[gp]=bi0; idx[gp+1]=bi1; idx[gp+2]=bi2;
    wgt[gp]=r0/s; wgt[gp+1]=r1/s; wgt[gp+2]=r2/s;
  }
}

// ---------------- K2 (slim): unknow_feats [b][c][n] -> uft [b][n][256] bf16 ----------------
__global__ __launch_bounds__(256) void uft_k(const float* __restrict__ uf,
                                             unsigned short* __restrict__ uft){
  int b  = blockIdx.x >> 8;
  int n0 = (blockIdx.x & 255) * 64;
  int t = threadIdx.x;
  __shared__ float tile[64][65];
  for (int cc=0; cc<4; ++cc){
    int c0 = cc*64;
    __syncthreads();
    #pragma unroll
    for (int p=0;p<16;p++){
      int row = p*4 + (t>>6), col = t&63;
      tile[row][col] = uf[((size_t)b*C1_ + c0+row)*N_ + n0+col];
    }
    __syncthreads();
    #pragma unroll
    for (int q=0;q<2;q++){
      int id = q*256 + t;
      int nl = id >> 3, c8 = (id & 7)*8;
      short8 o;
      #pragma unroll
      for (int e=0;e<8;++e) o[e] = (short)f2bfh(tile[c8+e][nl]);
      *(short8*)(uft + ((size_t)b*N_ + n0+nl)*CH_ + c0 + c8) = o;
    }
  }
}

// ---------------- GEMM: XCD-aware grid (batch -> XCD pair; o-twins co-XCD) ----------------
// MODE 1 (layer 1): B = [interp(gathered from kftb, k<512) | uft (global_load_lds, k>=512)]
// MODE 2 (layer 2): B = raw layer-1 output with fused relu(y*scale+shift) reg-staging
template<int KTOT, int MODE>
__global__ __launch_bounds__(256) void gemm_bt_k(const unsigned short* __restrict__ Wb,
                                                 const unsigned short* __restrict__ Bt,
                                                 unsigned short* __restrict__ Yt,
                                                 float* __restrict__ sump,   // [NSLOT][256]
                                                 float* __restrict__ sqp,    // [NSLOT][256]
                                                 const float* __restrict__ scalep,
                                                 const float* __restrict__ shiftp,
                                                 const unsigned short* __restrict__ kftb,
                                                 const int* __restrict__ idx,
                                                 const float* __restrict__ wgt){
  __shared__ short lsA[128*64];
  __shared__ short lsB[128*64];
  const int t = threadIdx.x, w = t>>6, l = t&63;
  // XCD-aware bijective remap: xcd = bid&7 owns batch xcd>>1 (4MB kftb slice = L2);
  // o-twins (s even/odd) have bids differing by 8 -> same XCD -> B-panel fetched once.
  const int bid  = blockIdx.x;
  const int xcd  = bid & 7;
  const int s    = bid >> 3;              // 0..127 per xcd
  const int batch= xcd >> 1;
  const int ntile= (xcd & 1)*64 + (s >> 1);
  const int nBase= batch*N_ + ntile*128;
  const int oBase= (s & 1)*128;
  const int wm = w>>1, wn = w&1, rl = l&15, hi = l>>4;
  f32x4 acc[4][4];
  #pragma unroll
  for (int i=0;i<4;i++)
    #pragma unroll
    for (int j=0;j<4;j++) acc[i][j] = (f32x4){0.f,0.f,0.f,0.f};
  const int srow8 = l>>3, sch = l&7;
  // MODE1: hoist per-row gather metadata (k-independent)
  int jj0[4], jj1[4], jj2[4];
  float ww0[4], ww1[4], ww2[4];
  const unsigned short* kfb = nullptr;
  if constexpr (MODE == 1){
    kfb = kftb + (size_t)batch*M_*C2_;
    #pragma unroll
    for (int j=0;j<4;++j){
      int row = w*8 + j*32 + srow8;
      size_t gp = (size_t)(nBase + row)*3;
      jj0[j] = idx[gp];   jj1[j] = idx[gp+1];   jj2[j] = idx[gp+2];
      ww0[j] = wgt[gp];   ww1[j] = wgt[gp+1];   ww2[j] = wgt[gp+2];
    }
  }
  for (int ks=0; ks<KTOT/64; ++ks){
    const int k0 = ks*64;
    __syncthreads();
    #pragma unroll
    for (int j=0;j<4;++j){
      int row = w*8 + j*32 + srow8;
      const unsigned short* gA = Wb + (size_t)(oBase+row)*KTOT + k0 + ((sch ^ (row&7))<<3);
      __builtin_amdgcn_global_load_lds((const __attribute__((address_space(1))) unsigned int*)gA,
          (__attribute__((address_space(3))) unsigned int*)(lsA + w*512 + j*2048), 16, 0, 0);
      if constexpr (MODE == 1){
        if (k0 >= C2_){
          const unsigned short* gB = Bt + (size_t)(nBase+row)*CH_ + (k0 - C2_) + ((sch ^ (row&7))<<3);
          __builtin_amdgcn_global_load_lds((const __attribute__((address_space(1))) unsigned int*)gB,
              (__attribute__((address_space(3))) unsigned int*)(lsB + w*512 + j*2048), 16, 0, 0);
        }
      }
    }
    if constexpr (MODE == 1){
      if (k0 < C2_){
        // fused three_interpolate: gather 3 rows from kftb, blend, write swizzled LDS
        #pragma unroll
        for (int j=0;j<4;++j){
          int row = w*8 + j*32 + srow8;
          int chb = k0 + ((sch ^ (row&7))<<3);
          const short8 a0 = *(const short8*)(kfb + (size_t)jj0[j]*C2_ + chb);
          const short8 a1 = *(const short8*)(kfb + (size_t)jj1[j]*C2_ + chb);
          const short8 a2 = *(const short8*)(kfb + (size_t)jj2[j]*C2_ + chb);
          float w0 = ww0[j], w1 = ww1[j], w2 = ww2[j];
          short8 o;
          #pragma unroll
          for (int e=0;e<8;++e){
            float f = w0*bf2f((unsigned short)a0[e])
                    + w1*bf2f((unsigned short)a1[e])
                    + w2*bf2f((unsigned short)a2[e]);
            o[e] = (short)f2bfh(f);
          }
          *(short8*)(lsB + w*512 + j*2048 + l*8) = o;
        }
      }
    }
    if constexpr (MODE == 2){
      #pragma unroll
      for (int j=0;j<4;++j){
        int row = w*8 + j*32 + srow8;
        int chb = k0 + ((sch ^ (row&7))<<3);
        const short8 v = *(const short8*)(Bt + (size_t)(nBase+row)*KTOT + chb);
        float4 sc0 = *(const float4*)(scalep + chb);
        float4 sc1 = *(const float4*)(scalep + chb + 4);
        float4 sh0 = *(const float4*)(shiftp + chb);
        float4 sh1 = *(const float4*)(shiftp + chb + 4);
        short8 o;
        float f0 = bf2f((unsigned short)v[0])*sc0.x + sh0.x; o[0] = (short)f2bfh(f0 > 0.f ? f0 : 0.f);
        float f1 = bf2f((unsigned short)v[1])*sc0.y + sh0.y; o[1] = (short)f2bfh(f1 > 0.f ? f1 : 0.f);
        float f2 = bf2f((unsigned short)v[2])*sc0.z + sh0.z; o[2] = (short)f2bfh(f2 > 0.f ? f2 : 0.f);
        float f3 = bf2f((unsigned short)v[3])*sc0.w + sh0.w; o[3] = (short)f2bfh(f3 > 0.f ? f3 : 0.f);
        float f4 = bf2f((unsigned short)v[4])*sc1.x + sh1.x; o[4] = (short)f2bfh(f4 > 0.f ? f4 : 0.f);
        float f5 = bf2f((unsigned short)v[5])*sc1.y + sh1.y; o[5] = (short)f2bfh(f5 > 0.f ? f5 : 0.f);
        float f6 = bf2f((unsigned short)v[6])*sc1.z + sh1.z; o[6] = (short)f2bfh(f6 > 0.f ? f6 : 0.f);
        float f7 = bf2f((unsigned short)v[7])*sc1.w + sh1.w; o[7] = (short)f2bfh(f7 > 0.f ? f7 : 0.f);
        *(short8*)(lsB + w*512 + j*2048 + l*8) = o;
      }
    }
    __syncthreads();
    #pragma unroll
    for (int kk=0;kk<2;++kk){
      short8 af[4], bfr[4];
      const int pc = ((kk*4 + hi) ^ (rl&7)) << 3;
      #pragma unroll
      for (int mi=0;mi<4;++mi) af[mi]  = *(const short8*)(lsA + (wm*64 + mi*16 + rl)*64 + pc);
      #pragma unroll
      for (int ni=0;ni<4;++ni) bfr[ni] = *(const short8*)(lsB + (wn*64 + ni*16 + rl)*64 + pc);
      #pragma unroll
      for (int mi=0;mi<4;++mi)
        #pragma unroll
        for (int ni=0;ni<4;++ni)
          acc[mi][ni] = __builtin_amdgcn_mfma_f32_16x16x32_bf16(af[mi], bfr[ni], acc[mi][ni], 0,0,0);
    }
  }
  // C-write (bf16)
  #pragma unroll
  for (int mi=0;mi<4;++mi)
    #pragma unroll
    for (int ni=0;ni<4;++ni){
      int n = nBase + wn*64 + ni*16 + rl;
      int o = oBase + wm*64 + mi*16 + hi*4;
      unsigned int lo = (unsigned int)f2bfh(acc[mi][ni][0]) | ((unsigned int)f2bfh(acc[mi][ni][1])<<16);
      unsigned int hi2= (unsigned int)f2bfh(acc[mi][ni][2]) | ((unsigned int)f2bfh(acc[mi][ni][3])<<16);
      uint2 vv; vv.x = lo; vv.y = hi2;
      *(uint2*)(Yt + (size_t)n*256 + o) = vv;
    }
  // fused BN stats -> slotted partial arrays (low contention)
  float s_[4][4], q_[4][4];
  #pragma unroll
  for (int mi=0;mi<4;++mi)
    #pragma unroll
    for (int j=0;j<4;++j){
      float s0 = acc[mi][0][j] + acc[mi][1][j] + acc[mi][2][j] + acc[mi][3][j];
      float q0 = acc[mi][0][j]*acc[mi][0][j];
      q0 = __builtin_fmaf(acc[mi][1][j], acc[mi][1][j], q0);
      q0 = __builtin_fmaf(acc[mi][2][j], acc[mi][2][j], q0);
      q0 = __builtin_fmaf(acc[mi][3][j], acc[mi][3][j], q0);
      s_[mi][j] = s0; q_[mi][j] = q0;
    }
  #pragma unroll
  for (int off=1; off<16; off<<=1){
    #pragma unroll
    for (int mi=0;mi<4;++mi)
      #pragma unroll
      for (int j=0;j<4;++j){
        s_[mi][j] += __shfl_xor(s_[mi][j], off);
        q_[mi][j] += __shfl_xor(q_[mi][j], off);
      }
  }
  if (rl == 0){
    const int slot = s & (NSLOT-1);
    #pragma unroll
    for (int mi=0;mi<4;++mi)
      #pragma unroll
      for (int j=0;j<4;++j){
        int o = oBase + wm*64 + mi*16 + hi*4 + j;
        atomicAdd(&sump[slot*256 + o], s_[mi][j]);
        atomicAdd(&sqp[slot*256 + o],  q_[mi][j]);
      }
  }
}

// ---------------- finalize: reduce slots -> BN scale/shift ----------------
__global__ __launch_bounds__(256) void finalize_k(const float* __restrict__ sump,
                                                  const float* __restrict__ sqp,
                                                  const float* __restrict__ g,
                                                  const float* __restrict__ bt,
                                                  float* __restrict__ scale,
                                                  float* __restrict__ shift){
  int t = threadIdx.x;
  float s = 0.f, q = 0.f;
  #pragma unroll 8
  for (int k=0;k<NSLOT;++k){
    s += sump[k*256 + t];
    q += sqp[k*256 + t];
  }
  float mean = s * (1.f/65536.f);
  float var  = q * (1.f/65536.f) - mean*mean;
  float sc = g[t] * rsqrtf(var + 1e-5f);
  scale[t] = sc;
  shift[t] = bt[t] - mean*sc;
}

// ---------------- final: y2T [n][256] bf16 -> out [b][256][N] f32 ----------------
__global__ __launch_bounds__(256) void out_k(const unsigned short* __restrict__ Yt,
                                             const float* __restrict__ scale,
                                             const float* __restrict__ shift,
                                             float* __restrict__ out){
  int gn0 = blockIdx.x*64;
  int o0  = blockIdx.y*64;
  int b = gn0 >> 14, n0 = gn0 & (N_-1);
  __shared__ unsigned short tile[64][66];
  int t = threadIdx.x;
  #pragma unroll
  for (int p=0;p<4;++p){
    int nl = p*16 + (t>>4), ol = (t&15)*4;
    const unsigned short* src = Yt + (size_t)(gn0+nl)*256 + o0 + ol;
    uint2 vv = *(const uint2*)src;
    tile[nl][ol+0] = (unsigned short)(vv.x & 0xffff);
    tile[nl][ol+1] = (unsigned short)(vv.x >> 16);
    tile[nl][ol+2] = (unsigned short)(vv.y & 0xffff);
    tile[nl][ol+3] = (unsigned short)(vv.y >> 16);
  }
  __syncthreads();
  #pragma unroll
  for (int p=0;p<4;++p){
    int ol = p*16 + (t>>4), nl = (t&15)*4;
    float sc = scale[o0+ol], sh = shift[o0+ol];
    float4 r;
    float f0 = bf2f(tile[nl+0][ol])*sc + sh; r.x = f0 > 0.f ? f0 : 0.f;
    float f1 = bf2f(tile[nl+1][ol])*sc + sh; r.y = f1 > 0.f ? f1 : 0.f;
    float f2v= bf2f(tile[nl+2][ol])*sc + sh; r.z = f2v > 0.f ? f2v : 0.f;
    float f3 = bf2f(tile[nl+3][ol])*sc + sh; r.w = f3 > 0.f ? f3 : 0.f;
    *(float4*)(out + ((size_t)(b*256 + o0+ol))*N_ + n0 + nl) = r;
  }
}

// ---------------- host launch ----------------
extern "C" void kernel_launch(void* const* d_in, const int* in_sizes, int n_in,
                              void* d_out, int out_size, void* d_ws, size_t ws_size,
                              hipStream_t stream) {
  const float* unknown     = (const float*)d_in[0];
  const float* known       = (const float*)d_in[1];
  const float* unknow_f    = (const float*)d_in[2];
  const float* known_f     = (const float*)d_in[3];
  const float* W1          = (const float*)d_in[4];
  // d_in[5] = b1 (cancels under training-mode BN)
  const float* g1          = (const float*)d_in[6];
  const float* bt1         = (const float*)d_in[7];
  const float* W2          = (const float*)d_in[8];
  // d_in[9] = b2 (cancels)
  const float* g2          = (const float*)d_in[10];
  const float* bt2         = (const float*)d_in[11];
  float* out = (float*)d_out;

  char* ws = (char*)d_ws;
  const size_t szUft  = (size_t)NG_*CH_*2;        //  33554432 (uft, later y2)
  const size_t szY    = (size_t)NG_*256*2;        //  33554432
  const size_t szKftb = (size_t)B_*M_*C2_*2;      //  16777216
  const size_t szIdx  = (size_t)NG_*3*4;
  const size_t szPart = (size_t)NSLOT*256*4;      //  65536 per array
  const size_t o_Uft  = 0;                         // later reused for y2 output
  const size_t o_Y    = szUft;                     // y1T (raw layer-1 output)
  const size_t o_kftb = o_Y + szY;
  const size_t o_idx  = o_kftb + szKftb;
  const size_t o_wgt  = o_idx + szIdx;
  const size_t o_W1b  = o_wgt + szIdx;
  const size_t o_W2b  = o_W1b + (size_t)CIN_*CH_*2;
  const size_t o_st   = o_W2b + (size_t)CH_*CH_*2; // 4 partial arrays + 4 scale/shift
  const size_t o_k4   = o_st + 4*szPart + 4*256*sizeof(float);

  unsigned short* Uft  = (unsigned short*)(ws + o_Uft);
  unsigned short* Y2   = (unsigned short*)(ws + o_Uft);  // reuse (uft dead after GEMM1)
  unsigned short* Y    = (unsigned short*)(ws + o_Y);    // y1T raw
  unsigned short* kftb = (unsigned short*)(ws + o_kftb);
  int*            idx  = (int*)(ws + o_idx);
  float*          wgt  = (float*)(ws + o_wgt);
  unsigned short* W1b  = (unsigned short*)(ws + o_W1b);
  unsigned short* W2b  = (unsigned short*)(ws + o_W2b);
  float* st = (float*)(ws + o_st);
  float4* k4 = (float4*)(ws + o_k4);
  float *sum1p = st;                    // [64][256]
  float *sq1p  = st + NSLOT*256;
  float *sum2p = st + 2*NSLOT*256;
  float *sq2p  = st + 3*NSLOT*256;
  float *scale1 = st + 4*NSLOT*256;
  float *shift1 = scale1 + 256;
  float *scale2 = scale1 + 512;
  float *shift2 = scale1 + 768;

  hipMemsetAsync(st, 0, 4*szPart, stream);

  prep_k<<<768, 256, 0, stream>>>(W1, W2, known, W1b, W2b, k4);
  kft_k<<<dim3(M_/64, C2_/64, B_), 256, 0, stream>>>(known_f, kftb);
  three_nn_k<<<B_*(N_/128), 512, 0, stream>>>(unknown, k4, idx, wgt);
  uft_k<<<B_*(N_/64), 256, 0, stream>>>(unknow_f, Uft);

  gemm_bt_k<CIN_, 1><<<NG_/64, 256, 0, stream>>>(W1b, Uft, Y, sum1p, sq1p,
                                                 nullptr, nullptr, kftb, idx, wgt);
  finalize_k<<<1, 256, 0, stream>>>(sum1p, sq1p, g1, bt1, scale1, shift1);

  gemm_bt_k<CH_, 2><<<NG_/64, 256, 0, stream>>>(W2b, Y, Y2, sum2p, sq2p,
                                                scale1, shift1, nullptr, nullptr, nullptr);
  finalize_k<<<1, 256, 0, stream>>>(sum2p, sq2p, g2, bt2, scale2, shift2);
  out_k<<<dim3(NG_/64, 4), 256, 0, stream>>>(Y2, scale2, shift2, out);
}

// Round 19
// 237.604 us; speedup vs baseline: 1.2123x; 1.0376x over previous
//
#include <hip/hip_runtime.h>
#include <hip/hip_bf16.h>
#include <stdint.h>
#include <stddef.h>

#define B_   4
#define N_   16384
#define M_   4096
#define C1_  256
#define C2_  512
#define CIN_ 768
#define CH_  256
#define NG_  (B_*N_)   // 65536
#define NSLOT 64

typedef __attribute__((ext_vector_type(8))) short short8;
typedef __attribute__((ext_vector_type(4))) float f32x4;

__device__ __forceinline__ float bf2f(unsigned short u){
  union { unsigned int i; float f; } v; v.i = ((unsigned int)u)<<16; return v.f;
}
// pack via compiler-lowered cast (pairs into v_cvt_pk_bf16_f32 on gfx950)
__device__ __forceinline__ unsigned short f2bfh(float f){
  __hip_bfloat16 h = __float2bfloat16(f);
  return *reinterpret_cast<unsigned short*>(&h);
}

// ---------------- prep: W1/W2 -> bf16, known -> K4 ----------------
__global__ __launch_bounds__(256) void prep_k(const float* __restrict__ W1,
                                              const float* __restrict__ W2,
                                              const float* __restrict__ kn,
                                              unsigned short* __restrict__ W1b,
                                              unsigned short* __restrict__ W2b,
                                              float4* __restrict__ k4){
  int i = blockIdx.x*256 + threadIdx.x;
  if (i < CIN_*CH_) W1b[i] = f2bfh(W1[i]);
  if (i < CH_*CH_)  W2b[i] = f2bfh(W2[i]);
  if (i < B_*M_){
    float x = kn[3*i], y = kn[3*i+1], z = kn[3*i+2];
    float4 v; v.x = -2.f*x; v.y = -2.f*y; v.z = -2.f*z; v.w = x*x+y*y+z*z;
    k4[i] = v;
  }
}

// ---------------- K0: known_feats [b][c][m] f32 -> kftb [b][m][c] bf16 ----------------
__global__ __launch_bounds__(256) void kft_k(const float* __restrict__ kf,
                                             unsigned short* __restrict__ kftb){
  int m0 = blockIdx.x*64, c0 = blockIdx.y*64, b = blockIdx.z;
  __shared__ float tile[64][65];
  int t = threadIdx.x;
  #pragma unroll
  for (int p=0;p<16;p++){
    int row = p*4 + (t>>6), col = t&63;
    tile[row][col] = kf[((size_t)b*C2_ + c0+row)*M_ + m0+col];
  }
  __syncthreads();
  #pragma unroll
  for (int q=0;q<2;q++){
    int id = q*256 + t;
    int ml = id >> 3, c8 = (id & 7)*8;
    short8 o;
    #pragma unroll
    for (int e=0;e<8;++e) o[e] = (short)f2bfh(tile[c8+e][ml]);
    *(short8*)(kftb + ((size_t)b*M_ + m0+ml)*C2_ + c0 + c8) = o;
  }
}

// ---------------- K1: three_nn + fused uft transpose ----------------
// Scan phase is VALU-bound with idle memory pipes; the uft transpose for this
// block's own 128-point window is appended, reusing the dead LDS table.
__global__ __launch_bounds__(512) void three_nn_k(const float* __restrict__ unk,
                                                  const float4* __restrict__ k4,
                                                  const float* __restrict__ uf,
                                                  int* __restrict__ idx,
                                                  float* __restrict__ wgt,
                                                  unsigned short* __restrict__ uft){
  __shared__ __align__(16) char smem[65536];   // 64 KB: table -> merge arrays -> f32 tile
  float4* kl = (float4*)smem;
  float*  sd = (float*)smem;                   // sd[24][128] after aliasing
  int*    si = (int*)(smem + 24*128*4);        // si[24][128]
  int b  = blockIdx.x >> 7;                    // 128 blocks of 128 points per batch
  int n0 = (blockIdx.x & 127) * 128;
  int t = threadIdx.x;
  int w = t >> 6, l = t & 63;                  // w = part 0..7
  const float4* src = k4 + (size_t)b*M_;
  #pragma unroll
  for (int i=0;i<8;++i) kl[i*512 + t] = src[i*512 + t];
  const float* upA = unk + ((size_t)b*N_ + n0 + l)*3;
  const float* upB = unk + ((size_t)b*N_ + n0 + 64 + l)*3;
  float ax=upA[0], ay=upA[1], az=upA[2];
  float bx=upB[0], by=upB[1], bz=upB[2];
  __syncthreads();
  float a0=1e30f,a1=1e30f,a2=1e30f; int ia0=0,ia1=0,ia2=0;
  float b0=1e30f,b1=1e30f,b2=1e30f; int ib0=0,ib1=0,ib2=0;
  const float4* kp = kl + w*512;
  const int mbase = w*512;
  #pragma unroll 8
  for (int m=0;m<512;++m){
    float4 kq = kp[m];                         // wave-uniform LDS broadcast
    int mi = mbase + m;
    float da = __builtin_fmaf(ax,kq.x, __builtin_fmaf(ay,kq.y, __builtin_fmaf(az,kq.z, kq.w)));
    float db = __builtin_fmaf(bx,kq.x, __builtin_fmaf(by,kq.y, __builtin_fmaf(bz,kq.z, kq.w)));
    {
      bool c0 = da < a0, c1 = da < a1, c2 = da < a2;
      int tA = c1 ? ia1 : mi;  ia2 = c2 ? tA : ia2;
      int tB = c0 ? ia0 : mi;  ia1 = c1 ? tB : ia1;
      ia0 = c0 ? mi : ia0;
      float n1 = __builtin_amdgcn_fmed3f(da, a0, a1);
      float n2 = __builtin_amdgcn_fmed3f(da, a1, a2);
      a0 = fminf(da, a0); a1 = n1; a2 = n2;
    }
    {
      bool c0 = db < b0, c1 = db < b1, c2 = db < b2;
      int tA = c1 ? ib1 : mi;  ib2 = c2 ? tA : ib2;
      int tB = c0 ? ib0 : mi;  ib1 = c1 ? tB : ib1;
      ib0 = c0 ? mi : ib0;
      float n1 = __builtin_amdgcn_fmed3f(db, b0, b1);
      float n2 = __builtin_amdgcn_fmed3f(db, b1, b2);
      b0 = fminf(db, b0); b1 = n1; b2 = n2;
    }
  }
  __syncthreads();                             // all table reads done -> safe to alias
  sd[(w*3+0)*128 + l] = a0;  sd[(w*3+0)*128 + 64 + l] = b0;
  sd[(w*3+1)*128 + l] = a1;  sd[(w*3+1)*128 + 64 + l] = b1;
  sd[(w*3+2)*128 + l] = a2;  sd[(w*3+2)*128 + 64 + l] = b2;
  si[(w*3+0)*128 + l] = ia0; si[(w*3+0)*128 + 64 + l] = ib0;
  si[(w*3+1)*128 + l] = ia1; si[(w*3+1)*128 + 64 + l] = ib1;
  si[(w*3+2)*128 + l] = ia2; si[(w*3+2)*128 + 64 + l] = ib2;
  __syncthreads();
  if (t < 128) {
    float bd0=1e30f,bd1=1e30f,bd2=1e30f; int bi0=0,bi1=0,bi2=0;
    #pragma unroll
    for (int q=0;q<24;++q){                    // part-major order -> stable ties
      float d = sd[q*128 + t]; int ii = si[q*128 + t];
      bool c0 = d < bd0, c1 = d < bd1, c2 = d < bd2;
      int tA = c1 ? bi1 : ii;  bi2 = c2 ? tA : bi2;
      int tB = c0 ? bi0 : ii;  bi1 = c1 ? tB : bi1;
      bi0 = c0 ? ii : bi0;
      float nd1 = __builtin_amdgcn_fmed3f(d, bd0, bd1);
      float nd2 = __builtin_amdgcn_fmed3f(d, bd1, bd2);
      bd0 = fminf(d, bd0); bd1 = nd1; bd2 = nd2;
    }
    int np = n0 + t;
    const float* upt = unk + ((size_t)b*N_ + np)*3;
    float x = upt[0], y = upt[1], z = upt[2];
    float uu0 = x*x + y*y + z*z;
    float t0 = fmaxf(bd0 + uu0, 0.f) + 1e-8f;
    float t1 = fmaxf(bd1 + uu0, 0.f) + 1e-8f;
    float t2 = fmaxf(bd2 + uu0, 0.f) + 1e-8f;
    float r0 = 1.f/t0, r1 = 1.f/t1, r2 = 1.f/t2;
    float s = r0+r1+r2;
    size_t gp = ((size_t)b*N_ + np)*3;
    idx[gp]=bi0; idx[gp+1]=bi1; idx[gp+2]=bi2;
    wgt[gp]=r0/s; wgt[gp+1]=r1/s; wgt[gp+2]=r2/s;
  }
  // ---- fused uft transpose: uf [b][c][n0..n0+127] f32 -> uft [b][n][256] bf16 ----
  float* tf = (float*)smem;                    // tile [64][129] f32 (33 KB), aliases dead LDS
  for (int cc=0; cc<4; ++cc){
    int c0 = cc*64;
    __syncthreads();                           // prior phase (merge / prev chunk) done
    #pragma unroll
    for (int p=0;p<16;++p){
      int row = p*4 + (t>>7);                  // 0..63
      int col = t & 127;                       // 0..127
      tf[row*129 + col] = uf[((size_t)b*C1_ + c0 + row)*N_ + n0 + col];
    }
    __syncthreads();
    #pragma unroll
    for (int q=0;q<2;++q){
      int id = q*512 + t;                      // 0..1023
      int nl = id >> 3;                        // 0..127
      int c8 = (id & 7)*8;
      short8 o;
      #pragma unroll
      for (int e=0;e<8;++e) o[e] = (short)f2bfh(tf[(c8+e)*129 + nl]);
      *(short8*)(uft + ((size_t)b*N_ + n0 + nl)*CH_ + c0 + c8) = o;
    }
  }
}

// ---------------- GEMM: XCD-aware grid (batch -> XCD pair; o-twins co-XCD) ----------------
// MODE 1 (layer 1): B = [interp(gathered from kftb, k<512) | uft (global_load_lds, k>=512)]
// MODE 2 (layer 2): B = raw layer-1 output with fused relu(y*scale+shift) reg-staging
template<int KTOT, int MODE>
__global__ __launch_bounds__(256) void gemm_bt_k(const unsigned short* __restrict__ Wb,
                                                 const unsigned short* __restrict__ Bt,
                                                 unsigned short* __restrict__ Yt,
                                                 float* __restrict__ sump,   // [NSLOT][256]
                                                 float* __restrict__ sqp,    // [NSLOT][256]
                                                 const float* __restrict__ scalep,
                                                 const float* __restrict__ shiftp,
                                                 const unsigned short* __restrict__ kftb,
                                                 const int* __restrict__ idx,
                                                 const float* __restrict__ wgt){
  __shared__ short lsA[128*64];
  __shared__ short lsB[128*64];
  const int t = threadIdx.x, w = t>>6, l = t&63;
  const int bid  = blockIdx.x;
  const int xcd  = bid & 7;
  const int s    = bid >> 3;              // 0..127 per xcd
  const int batch= xcd >> 1;
  const int ntile= (xcd & 1)*64 + (s >> 1);
  const int nBase= batch*N_ + ntile*128;
  const int oBase= (s & 1)*128;
  const int wm = w>>1, wn = w&1, rl = l&15, hi = l>>4;
  f32x4 acc[4][4];
  #pragma unroll
  for (int i=0;i<4;i++)
    #pragma unroll
    for (int j=0;j<4;j++) acc[i][j] = (f32x4){0.f,0.f,0.f,0.f};
  const int srow8 = l>>3, sch = l&7;
  int jj0[4], jj1[4], jj2[4];
  float ww0[4], ww1[4], ww2[4];
  const unsigned short* kfb = nullptr;
  if constexpr (MODE == 1){
    kfb = kftb + (size_t)batch*M_*C2_;
    #pragma unroll
    for (int j=0;j<4;++j){
      int row = w*8 + j*32 + srow8;
      size_t gp = (size_t)(nBase + row)*3;
      jj0[j] = idx[gp];   jj1[j] = idx[gp+1];   jj2[j] = idx[gp+2];
      ww0[j] = wgt[gp];   ww1[j] = wgt[gp+1];   ww2[j] = wgt[gp+2];
    }
  }
  for (int ks=0; ks<KTOT/64; ++ks){
    const int k0 = ks*64;
    __syncthreads();
    #pragma unroll
    for (int j=0;j<4;++j){
      int row = w*8 + j*32 + srow8;
      const unsigned short* gA = Wb + (size_t)(oBase+row)*KTOT + k0 + ((sch ^ (row&7))<<3);
      __builtin_amdgcn_global_load_lds((const __attribute__((address_space(1))) unsigned int*)gA,
          (__attribute__((address_space(3))) unsigned int*)(lsA + w*512 + j*2048), 16, 0, 0);
      if constexpr (MODE == 1){
        if (k0 >= C2_){
          const unsigned short* gB = Bt + (size_t)(nBase+row)*CH_ + (k0 - C2_) + ((sch ^ (row&7))<<3);
          __builtin_amdgcn_global_load_lds((const __attribute__((address_space(1))) unsigned int*)gB,
              (__attribute__((address_space(3))) unsigned int*)(lsB + w*512 + j*2048), 16, 0, 0);
        }
      }
    }
    if constexpr (MODE == 1){
      if (k0 < C2_){
        #pragma unroll
        for (int j=0;j<4;++j){
          int row = w*8 + j*32 + srow8;
          int chb = k0 + ((sch ^ (row&7))<<3);
          const short8 a0 = *(const short8*)(kfb + (size_t)jj0[j]*C2_ + chb);
          const short8 a1 = *(const short8*)(kfb + (size_t)jj1[j]*C2_ + chb);
          const short8 a2 = *(const short8*)(kfb + (size_t)jj2[j]*C2_ + chb);
          float w0 = ww0[j], w1 = ww1[j], w2 = ww2[j];
          short8 o;
          #pragma unroll
          for (int e=0;e<8;++e){
            float f = w0*bf2f((unsigned short)a0[e])
                    + w1*bf2f((unsigned short)a1[e])
                    + w2*bf2f((unsigned short)a2[e]);
            o[e] = (short)f2bfh(f);
          }
          *(short8*)(lsB + w*512 + j*2048 + l*8) = o;
        }
      }
    }
    if constexpr (MODE == 2){
      #pragma unroll
      for (int j=0;j<4;++j){
        int row = w*8 + j*32 + srow8;
        int chb = k0 + ((sch ^ (row&7))<<3);
        const short8 v = *(const short8*)(Bt + (size_t)(nBase+row)*KTOT + chb);
        float4 sc0 = *(const float4*)(scalep + chb);
        float4 sc1 = *(const float4*)(scalep + chb + 4);
        float4 sh0 = *(const float4*)(shiftp + chb);
        float4 sh1 = *(const float4*)(shiftp + chb + 4);
        short8 o;
        float f0 = bf2f((unsigned short)v[0])*sc0.x + sh0.x; o[0] = (short)f2bfh(f0 > 0.f ? f0 : 0.f);
        float f1 = bf2f((unsigned short)v[1])*sc0.y + sh0.y; o[1] = (short)f2bfh(f1 > 0.f ? f1 : 0.f);
        float f2 = bf2f((unsigned short)v[2])*sc0.z + sh0.z; o[2] = (short)f2bfh(f2 > 0.f ? f2 : 0.f);
        float f3 = bf2f((unsigned short)v[3])*sc0.w + sh0.w; o[3] = (short)f2bfh(f3 > 0.f ? f3 : 0.f);
        float f4 = bf2f((unsigned short)v[4])*sc1.x + sh1.x; o[4] = (short)f2bfh(f4 > 0.f ? f4 : 0.f);
        float f5 = bf2f((unsigned short)v[5])*sc1.y + sh1.y; o[5] = (short)f2bfh(f5 > 0.f ? f5 : 0.f);
        float f6 = bf2f((unsigned short)v[6])*sc1.z + sh1.z; o[6] = (short)f2bfh(f6 > 0.f ? f6 : 0.f);
        float f7 = bf2f((unsigned short)v[7])*sc1.w + sh1.w; o[7] = (short)f2bfh(f7 > 0.f ? f7 : 0.f);
        *(short8*)(lsB + w*512 + j*2048 + l*8) = o;
      }
    }
    __syncthreads();
    #pragma unroll
    for (int kk=0;kk<2;++kk){
      short8 af[4], bfr[4];
      const int pc = ((kk*4 + hi) ^ (rl&7)) << 3;
      #pragma unroll
      for (int mi=0;mi<4;++mi) af[mi]  = *(const short8*)(lsA + (wm*64 + mi*16 + rl)*64 + pc);
      #pragma unroll
      for (int ni=0;ni<4;++ni) bfr[ni] = *(const short8*)(lsB + (wn*64 + ni*16 + rl)*64 + pc);
      #pragma unroll
      for (int mi=0;mi<4;++mi)
        #pragma unroll
        for (int ni=0;ni<4;++ni)
          acc[mi][ni] = __builtin_amdgcn_mfma_f32_16x16x32_bf16(af[mi], bfr[ni], acc[mi][ni], 0,0,0);
    }
  }
  // C-write (bf16)
  #pragma unroll
  for (int mi=0;mi<4;++mi)
    #pragma unroll
    for (int ni=0;ni<4;++ni){
      int n = nBase + wn*64 + ni*16 + rl;
      int o = oBase + wm*64 + mi*16 + hi*4;
      unsigned int lo = (unsigned int)f2bfh(acc[mi][ni][0]) | ((unsigned int)f2bfh(acc[mi][ni][1])<<16);
      unsigned int hi2= (unsigned int)f2bfh(acc[mi][ni][2]) | ((unsigned int)f2bfh(acc[mi][ni][3])<<16);
      uint2 vv; vv.x = lo; vv.y = hi2;
      *(uint2*)(Yt + (size_t)n*256 + o) = vv;
    }
  // fused BN stats -> slotted partial arrays (low contention)
  float s_[4][4], q_[4][4];
  #pragma unroll
  for (int mi=0;mi<4;++mi)
    #pragma unroll
    for (int j=0;j<4;++j){
      float s0 = acc[mi][0][j] + acc[mi][1][j] + acc[mi][2][j] + acc[mi][3][j];
      float q0 = acc[mi][0][j]*acc[mi][0][j];
      q0 = __builtin_fmaf(acc[mi][1][j], acc[mi][1][j], q0);
      q0 = __builtin_fmaf(acc[mi][2][j], acc[mi][2][j], q0);
      q0 = __builtin_fmaf(acc[mi][3][j], acc[mi][3][j], q0);
      s_[mi][j] = s0; q_[mi][j] = q0;
    }
  #pragma unroll
  for (int off=1; off<16; off<<=1){
    #pragma unroll
    for (int mi=0;mi<4;++mi)
      #pragma unroll
      for (int j=0;j<4;++j){
        s_[mi][j] += __shfl_xor(s_[mi][j], off);
        q_[mi][j] += __shfl_xor(q_[mi][j], off);
      }
  }
  if (rl == 0){
    const int slot = s & (NSLOT-1);
    #pragma unroll
    for (int mi=0;mi<4;++mi)
      #pragma unroll
      for (int j=0;j<4;++j){
        int o = oBase + wm*64 + mi*16 + hi*4 + j;
        atomicAdd(&sump[slot*256 + o], s_[mi][j]);
        atomicAdd(&sqp[slot*256 + o],  q_[mi][j]);
      }
  }
}

// ---------------- finalize: reduce slots -> BN scale/shift ----------------
__global__ __launch_bounds__(256) void finalize_k(const float* __restrict__ sump,
                                                  const float* __restrict__ sqp,
                                                  const float* __restrict__ g,
                                                  const float* __restrict__ bt,
                                                  float* __restrict__ scale,
                                                  float* __restrict__ shift){
  int t = threadIdx.x;
  float s = 0.f, q = 0.f;
  #pragma unroll 8
  for (int k=0;k<NSLOT;++k){
    s += sump[k*256 + t];
    q += sqp[k*256 + t];
  }
  float mean = s * (1.f/65536.f);
  float var  = q * (1.f/65536.f) - mean*mean;
  float sc = g[t] * rsqrtf(var + 1e-5f);
  scale[t] = sc;
  shift[t] = bt[t] - mean*sc;
}

// ---------------- final: y2T [n][256] bf16 -> out [b][256][N] f32 ----------------
__global__ __launch_bounds__(256) void out_k(const unsigned short* __restrict__ Yt,
                                             const float* __restrict__ scale,
                                             const float* __restrict__ shift,
                                             float* __restrict__ out){
  int gn0 = blockIdx.x*64;
  int o0  = blockIdx.y*64;
  int b = gn0 >> 14, n0 = gn0 & (N_-1);
  __shared__ unsigned short tile[64][66];
  int t = threadIdx.x;
  #pragma unroll
  for (int p=0;p<4;++p){
    int nl = p*16 + (t>>4), ol = (t&15)*4;
    const unsigned short* src = Yt + (size_t)(gn0+nl)*256 + o0 + ol;
    uint2 vv = *(const uint2*)src;
    tile[nl][ol+0] = (unsigned short)(vv.x & 0xffff);
    tile[nl][ol+1] = (unsigned short)(vv.x >> 16);
    tile[nl][ol+2] = (unsigned short)(vv.y & 0xffff);
    tile[nl][ol+3] = (unsigned short)(vv.y >> 16);
  }
  __syncthreads();
  #pragma unroll
  for (int p=0;p<4;++p){
    int ol = p*16 + (t>>4), nl = (t&15)*4;
    float sc = scale[o0+ol], sh = shift[o0+ol];
    float4 r;
    float f0 = bf2f(tile[nl+0][ol])*sc + sh; r.x = f0 > 0.f ? f0 : 0.f;
    float f1 = bf2f(tile[nl+1][ol])*sc + sh; r.y = f1 > 0.f ? f1 : 0.f;
    float f2v= bf2f(tile[nl+2][ol])*sc + sh; r.z = f2v > 0.f ? f2v : 0.f;
    float f3 = bf2f(tile[nl+3][ol])*sc + sh; r.w = f3 > 0.f ? f3 : 0.f;
    *(float4*)(out + ((size_t)(b*256 + o0+ol))*N_ + n0 + nl) = r;
  }
}

// ---------------- host launch ----------------
extern "C" void kernel_launch(void* const* d_in, const int* in_sizes, int n_in,
                              void* d_out, int out_size, void* d_ws, size_t ws_size,
                              hipStream_t stream) {
  const float* unknown     = (const float*)d_in[0];
  const float* known       = (const float*)d_in[1];
  const float* unknow_f    = (const float*)d_in[2];
  const float* known_f     = (const float*)d_in[3];
  const float* W1          = (const float*)d_in[4];
  // d_in[5] = b1 (cancels under training-mode BN)
  const float* g1          = (const float*)d_in[6];
  const float* bt1         = (const float*)d_in[7];
  const float* W2          = (const float*)d_in[8];
  // d_in[9] = b2 (cancels)
  const float* g2          = (const float*)d_in[10];
  const float* bt2         = (const float*)d_in[11];
  float* out = (float*)d_out;

  char* ws = (char*)d_ws;
  const size_t szUft  = (size_t)NG_*CH_*2;        //  33554432 (uft, later y2)
  const size_t szY    = (size_t)NG_*256*2;        //  33554432
  const size_t szKftb = (size_t)B_*M_*C2_*2;      //  16777216
  const size_t szIdx  = (size_t)NG_*3*4;
  const size_t szPart = (size_t)NSLOT*256*4;      //  65536 per array
  const size_t o_Uft  = 0;                         // later reused for y2 output
  const size_t o_Y    = szUft;                     // y1T (raw layer-1 output)
  const size_t o_kftb = o_Y + szY;
  const size_t o_idx  = o_kftb + szKftb;
  const size_t o_wgt  = o_idx + szIdx;
  const size_t o_W1b  = o_wgt + szIdx;
  const size_t o_W2b  = o_W1b + (size_t)CIN_*CH_*2;
  const size_t o_st   = o_W2b + (size_t)CH_*CH_*2; // 4 partial arrays + 4 scale/shift
  const size_t o_k4   = o_st + 4*szPart + 4*256*sizeof(float);

  unsigned short* Uft  = (unsigned short*)(ws + o_Uft);
  unsigned short* Y2   = (unsigned short*)(ws + o_Uft);  // reuse (uft dead after GEMM1)
  unsigned short* Y    = (unsigned short*)(ws + o_Y);    // y1T raw
  unsigned short* kftb = (unsigned short*)(ws + o_kftb);
  int*            idx  = (int*)(ws + o_idx);
  float*          wgt  = (float*)(ws + o_wgt);
  unsigned short* W1b  = (unsigned short*)(ws + o_W1b);
  unsigned short* W2b  = (unsigned short*)(ws + o_W2b);
  float* st = (float*)(ws + o_st);
  float4* k4 = (float4*)(ws + o_k4);
  float *sum1p = st;                    // [64][256]
  float *sq1p  = st + NSLOT*256;
  float *sum2p = st + 2*NSLOT*256;
  float *sq2p  = st + 3*NSLOT*256;
  float *scale1 = st + 4*NSLOT*256;
  float *shift1 = scale1 + 256;
  float *scale2 = scale1 + 512;
  float *shift2 = scale1 + 768;

  hipMemsetAsync(st, 0, 4*szPart, stream);

  prep_k<<<768, 256, 0, stream>>>(W1, W2, known, W1b, W2b, k4);
  kft_k<<<dim3(M_/64, C2_/64, B_), 256, 0, stream>>>(known_f, kftb);
  three_nn_k<<<B_*(N_/128), 512, 0, stream>>>(unknown, k4, unknow_f, idx, wgt, Uft);

  gemm_bt_k<CIN_, 1><<<NG_/64, 256, 0, stream>>>(W1b, Uft, Y, sum1p, sq1p,
                                                 nullptr, nullptr, kftb, idx, wgt);
  finalize_k<<<1, 256, 0, stream>>>(sum1p, sq1p, g1, bt1, scale1, shift1);

  gemm_bt_k<CH_, 2><<<NG_/64, 256, 0, stream>>>(W2b, Y, Y2, sum2p, sq2p,
                                                scale1, shift1, nullptr, nullptr, nullptr);
  finalize_k<<<1, 256, 0, stream>>>(sum2p, sq2p, g2, bt2, scale2, shift2);
  out_k<<<dim3(NG_/64, 4), 256, 0, stream>>>(Y2, scale2, shift2, out);
}